// Round 1
// baseline (1631.598 us; speedup 1.0000x reference)
//
#include <hip/hip_runtime.h>
#include <math.h>

#define N_NODES 50000
#define E_EDGES 800000
#define D_DIM   128
#define H_HEADS 8
#define DH_DIM  16
#define DFF     512

// ---------------- helpers ----------------
__device__ __forceinline__ unsigned int fkey(float f) {
    unsigned int u = __float_as_uint(f);
    return (u & 0x80000000u) ? ~u : (u | 0x80000000u);
}
__device__ __forceinline__ float funkey(unsigned int k) {
    return (k & 0x80000000u) ? __uint_as_float(k ^ 0x80000000u)
                             : __uint_as_float(~k);
}
__device__ __forceinline__ float lrelu(float v) { return v > 0.f ? v : 0.01f * v; }

// ---------------- zero init ----------------
__global__ void k_zero(float* __restrict__ out, float* __restrict__ ssum,
                       unsigned int* __restrict__ mkey) {
    int i = blockIdx.x * 256 + threadIdx.x;
    if (i < N_NODES * D_DIM) out[i] = 0.f;
    if (i < N_NODES * H_HEADS) { ssum[i] = 0.f; mkey[i] = 0u; }
}

// ---------------- z = x @ Wp  (Wp[d][c] = W_fc[c>>4][d][c&15]) ----------------
// 64 rows/block, 512 threads, 4r x 4c register tile
__global__ __launch_bounds__(512) void k_proj(const float* __restrict__ x,
                                              const float* __restrict__ Wfc,
                                              float* __restrict__ z) {
    __shared__ float xT[128 * 68];   // xT[d][r], stride 68
    __shared__ float Wp[128 * 132];  // Wp[d][c], stride 132
    int t = threadIdx.x;
    int r0 = blockIdx.x * 64;
    // load x rows transposed
    for (int lin = t; lin < 64 * 128; lin += 512) {
        int r = lin >> 7, d = lin & 127;
        float v = 0.f;
        if (r0 + r < N_NODES) v = x[(r0 + r) * 128 + d];
        xT[d * 68 + r] = v;
    }
    // load permuted W_fc: per float4 over (d, h, q)
    for (int lin = t; lin < 4096; lin += 512) {
        int d = lin >> 5;
        int rem = lin & 31;
        int h = rem >> 2, q = (rem & 3) * 4;
        float4 w = *(const float4*)(Wfc + h * 2048 + d * 16 + q);
        *(float4*)&Wp[d * 132 + h * 16 + q] = w;
    }
    __syncthreads();
    int ct = t & 31, rt = t >> 5;
    int c0 = ct * 4, rr = rt * 4;
    float acc[4][4] = {};
    #pragma unroll 4
    for (int d = 0; d < 128; ++d) {
        float4 xv = *(const float4*)&xT[d * 68 + rr];
        float4 wv = *(const float4*)&Wp[d * 132 + c0];
        float xa[4] = {xv.x, xv.y, xv.z, xv.w};
        float wa[4] = {wv.x, wv.y, wv.z, wv.w};
        #pragma unroll
        for (int i = 0; i < 4; ++i)
            #pragma unroll
            for (int j = 0; j < 4; ++j) acc[i][j] += xa[i] * wa[j];
    }
    #pragma unroll
    for (int i = 0; i < 4; ++i) {
        int r = r0 + rr + i;
        if (r < N_NODES)
            *(float4*)&z[r * 128 + c0] =
                make_float4(acc[i][0], acc[i][1], acc[i][2], acc[i][3]);
    }
}

// ---------------- el/er ----------------
__global__ void k_el_er(const float* __restrict__ z, const float* __restrict__ a_l,
                        const float* __restrict__ a_r, float* __restrict__ el,
                        float* __restrict__ er) {
    int i = blockIdx.x * 256 + threadIdx.x;  // n*8 + h
    if (i >= N_NODES * H_HEADS) return;
    int h = i & 7;
    const float* zp = z + (size_t)(i >> 3) * 128 + h * 16;
    float sl = 0.f, sr = 0.f;
    #pragma unroll
    for (int k = 0; k < 16; ++k) {
        float v = zp[k];
        sl += v * a_l[h * 16 + k];
        sr += v * a_r[h * 16 + k];
    }
    el[i] = sl;
    er[i] = sr;
}

// ---------------- segment max over dst ----------------
__global__ void k_emax(const int* __restrict__ es, const int* __restrict__ ed,
                       const float* __restrict__ el, const float* __restrict__ er,
                       unsigned int* __restrict__ mkey) {
    int e = blockIdx.x * 256 + threadIdx.x;
    int s = es[e], d = ed[e];
    float le[8], re[8];
    *(float4*)&le[0] = *(const float4*)(el + s * 8);
    *(float4*)&le[4] = *(const float4*)(el + s * 8 + 4);
    *(float4*)&re[0] = *(const float4*)(er + d * 8);
    *(float4*)&re[4] = *(const float4*)(er + d * 8 + 4);
    #pragma unroll
    for (int h = 0; h < 8; ++h) {
        float v = lrelu(le[h] + re[h]);
        atomicMax(&mkey[d * 8 + h], fkey(v));
    }
}

// ---------------- exp + segment sum, store ee ----------------
__global__ void k_esum(const int* __restrict__ es, const int* __restrict__ ed,
                       const float* __restrict__ el, const float* __restrict__ er,
                       const unsigned int* __restrict__ mkey, float* __restrict__ ssum,
                       float* __restrict__ ee) {
    int e = blockIdx.x * 256 + threadIdx.x;
    int s = es[e], d = ed[e];
    float le[8], re[8];
    *(float4*)&le[0] = *(const float4*)(el + s * 8);
    *(float4*)&le[4] = *(const float4*)(el + s * 8 + 4);
    *(float4*)&re[0] = *(const float4*)(er + d * 8);
    *(float4*)&re[4] = *(const float4*)(er + d * 8 + 4);
    #pragma unroll
    for (int h = 0; h < 8; ++h) {
        float v = lrelu(le[h] + re[h]);
        float m = funkey(mkey[d * 8 + h]);
        float x = __expf(v - m);
        ee[e * 8 + h] = x;
        atomicAdd(&ssum[d * 8 + h], x);
    }
}

// ---------------- weighted scatter: one wave per edge ----------------
__global__ __launch_bounds__(256) void k_scatter(const int* __restrict__ es,
                                                 const int* __restrict__ ed,
                                                 const float* __restrict__ ee,
                                                 const float* __restrict__ ssum,
                                                 const float* __restrict__ z,
                                                 float* __restrict__ out) {
    int gid = blockIdx.x * 256 + threadIdx.x;
    int e = gid >> 6;
    int lane = threadIdx.x & 63;
    if (e >= E_EDGES) return;
    int s = es[e], d = ed[e];
    int h = lane >> 3;  // head for dims 2*lane, 2*lane+1
    float a = ee[e * 8 + h];
    float sv = ssum[d * 8 + h];
    a = a / fmaxf(sv, 1e-9f);
    float2 zv = *(const float2*)&z[(size_t)s * 128 + lane * 2];
    atomicAdd(&out[(size_t)d * 128 + lane * 2], a * zv.x);
    atomicAdd(&out[(size_t)d * 128 + lane * 2 + 1], a * zv.y);
}

// ---------------- fused elu+residual+LN+FFN ----------------
// 64 rows/block, 512 threads. LDS: uni(hb then lnT) + WL + interT ~ 138 KB
__global__ __launch_bounds__(512) void k_ffn(const float* __restrict__ x,
                                             const float* __restrict__ gamma,
                                             const float* __restrict__ beta,
                                             const float* __restrict__ W1,
                                             const float* __restrict__ b1,
                                             const float* __restrict__ W2,
                                             const float* __restrict__ b2,
                                             float* __restrict__ out) {
    __shared__ float uni[8704];     // hb[64][136] -> lnT[128][68]
    __shared__ float WL[128 * 132]; // W1 tile [d][fl] / W2 tile [fl][c]
    __shared__ float interT[128 * 68];
    __shared__ float muL[64], rsL[64];
    int t = threadIdx.x;
    int r0 = blockIdx.x * 64;

    // phase 0: h = x + elu(gat)
    for (int lin = t; lin < 64 * 128; lin += 512) {
        int r = lin >> 7, d = lin & 127;
        float v = 0.f;
        int gr = r0 + r;
        if (gr < N_NODES) {
            float g = out[(size_t)gr * 128 + d];
            g = g > 0.f ? g : expm1f(g);
            v = x[(size_t)gr * 128 + d] + g;
        }
        uni[r * 136 + d] = v;
    }
    __syncthreads();
    // LN stats: 8 threads per row
    {
        int r = t >> 3, j = t & 7;
        float sm = 0.f, sq = 0.f;
        for (int d = j; d < 128; d += 8) {
            float v = uni[r * 136 + d];
            sm += v; sq += v * v;
        }
        sm += __shfl_xor(sm, 1); sq += __shfl_xor(sq, 1);
        sm += __shfl_xor(sm, 2); sq += __shfl_xor(sq, 2);
        sm += __shfl_xor(sm, 4); sq += __shfl_xor(sq, 4);
        if (j == 0) {
            float mu = sm * (1.f / 128.f);
            float var = sq * (1.f / 128.f) - mu * mu;
            muL[r] = mu;
            rsL[r] = rsqrtf(var + 1e-5f);
        }
    }
    __syncthreads();
    // LN, transposed in place (uni reinterpreted as lnT[d][r], stride 68)
    float lnv[16];
    #pragma unroll
    for (int k = 0; k < 16; ++k) {
        int lin = t + k * 512;
        int r = lin >> 7, d = lin & 127;
        lnv[k] = (uni[r * 136 + d] - muL[r]) * rsL[r] * gamma[d] + beta[d];
    }
    __syncthreads();
    #pragma unroll
    for (int k = 0; k < 16; ++k) {
        int lin = t + k * 512;
        int r = lin >> 7, d = lin & 127;
        uni[d * 68 + r] = lnv[k];
    }
    __syncthreads();

    int ct = t & 31, rt = t >> 5;
    int c0 = ct * 4, rr = rt * 4;
    float oacc[4][4] = {};
    for (int tile = 0; tile < 4; ++tile) {
        int f0 = tile * 128;
        // W1 tile
        for (int lin = t; lin < 128 * 32; lin += 512) {
            int d = lin >> 5, q = (lin & 31) * 4;
            *(float4*)&WL[d * 132 + q] = *(const float4*)&W1[(size_t)d * 512 + f0 + q];
        }
        __syncthreads();
        float iacc[4][4] = {};
        #pragma unroll 4
        for (int d = 0; d < 128; ++d) {
            float4 lv = *(const float4*)&uni[d * 68 + rr];
            float4 wv = *(const float4*)&WL[d * 132 + c0];
            float la[4] = {lv.x, lv.y, lv.z, lv.w};
            float wa[4] = {wv.x, wv.y, wv.z, wv.w};
            #pragma unroll
            for (int ri = 0; ri < 4; ++ri)
                #pragma unroll
                for (int ci = 0; ci < 4; ++ci) iacc[ri][ci] += la[ri] * wa[ci];
        }
        // bias + relu -> interT[f][r]
        #pragma unroll
        for (int fi = 0; fi < 4; ++fi) {
            float bb = b1[f0 + c0 + fi];
            #pragma unroll
            for (int ri = 0; ri < 4; ++ri) {
                float v = iacc[ri][fi] + bb;
                interT[(c0 + fi) * 68 + rr + ri] = v > 0.f ? v : 0.f;
            }
        }
        __syncthreads();
        // W2 tile
        for (int lin = t; lin < 128 * 32; lin += 512) {
            int fl = lin >> 5, q = (lin & 31) * 4;
            *(float4*)&WL[fl * 132 + q] = *(const float4*)&W2[(size_t)(f0 + fl) * 128 + q];
        }
        __syncthreads();
        #pragma unroll 4
        for (int fl = 0; fl < 128; ++fl) {
            float4 iv = *(const float4*)&interT[fl * 68 + rr];
            float4 wv = *(const float4*)&WL[fl * 132 + c0];
            float ia[4] = {iv.x, iv.y, iv.z, iv.w};
            float wa[4] = {wv.x, wv.y, wv.z, wv.w};
            #pragma unroll
            for (int ri = 0; ri < 4; ++ri)
                #pragma unroll
                for (int ci = 0; ci < 4; ++ci) oacc[ri][ci] += ia[ri] * wa[ci];
        }
        __syncthreads();
    }
    // final: out = oacc + b2 + (x + elu(gat)), recompute h from globals
    float4 b2v = *(const float4*)&b2[c0];
    float ba[4] = {b2v.x, b2v.y, b2v.z, b2v.w};
    #pragma unroll
    for (int ri = 0; ri < 4; ++ri) {
        int gr = r0 + rr + ri;
        if (gr < N_NODES) {
            float4 gv = *(const float4*)&out[(size_t)gr * 128 + c0];
            float4 xv = *(const float4*)&x[(size_t)gr * 128 + c0];
            float ga[4] = {gv.x, gv.y, gv.z, gv.w};
            float xa[4] = {xv.x, xv.y, xv.z, xv.w};
            float o[4];
            #pragma unroll
            for (int ci = 0; ci < 4; ++ci) {
                float g = ga[ci] > 0.f ? ga[ci] : expm1f(ga[ci]);
                o[ci] = oacc[ri][ci] + ba[ci] + xa[ci] + g;
            }
            *(float4*)&out[(size_t)gr * 128 + c0] = make_float4(o[0], o[1], o[2], o[3]);
        }
    }
}

extern "C" void kernel_launch(void* const* d_in, const int* in_sizes, int n_in,
                              void* d_out, int out_size, void* d_ws, size_t ws_size,
                              hipStream_t stream) {
    const float* x     = (const float*)d_in[0];
    const float* Wfc   = (const float*)d_in[1];
    const float* a_l   = (const float*)d_in[2];
    const float* a_r   = (const float*)d_in[3];
    const float* gamma = (const float*)d_in[4];
    const float* beta  = (const float*)d_in[5];
    const float* W1    = (const float*)d_in[6];
    const float* b1    = (const float*)d_in[7];
    const float* W2    = (const float*)d_in[8];
    const float* b2    = (const float*)d_in[9];
    const int*   es    = (const int*)d_in[10];
    const int*   ed    = (const int*)d_in[11];
    float* out = (float*)d_out;

    float* ws = (float*)d_ws;
    float* z  = ws;                                   // N*128
    float* el = z + (size_t)N_NODES * 128;            // N*8
    float* er = el + N_NODES * 8;                     // N*8
    unsigned int* mkey = (unsigned int*)(er + N_NODES * 8);  // N*8
    float* ssum = (float*)(mkey + N_NODES * 8);       // N*8
    float* ee = ssum + N_NODES * 8;                   // E*8

    k_zero<<<dim3((N_NODES * D_DIM + 255) / 256), dim3(256), 0, stream>>>(out, ssum, mkey);
    k_proj<<<dim3((N_NODES + 63) / 64), dim3(512), 0, stream>>>(x, Wfc, z);
    k_el_er<<<dim3((N_NODES * H_HEADS + 255) / 256), dim3(256), 0, stream>>>(z, a_l, a_r, el, er);
    k_emax<<<dim3(E_EDGES / 256), dim3(256), 0, stream>>>(es, ed, el, er, mkey);
    k_esum<<<dim3(E_EDGES / 256), dim3(256), 0, stream>>>(es, ed, el, er, mkey, ssum, ee);
    k_scatter<<<dim3(E_EDGES / 4), dim3(256), 0, stream>>>(es, ed, ee, ssum, z, out);
    k_ffn<<<dim3((N_NODES + 63) / 64), dim3(512), 0, stream>>>(x, gamma, beta, W1, b1, W2, b2, out);
}

// Round 2
// 647.789 us; speedup vs baseline: 2.5187x; 2.5187x over previous
//
#include <hip/hip_runtime.h>
#include <math.h>

#define N_NODES 50000
#define E_EDGES 800000
#define D_DIM   128
#define H_HEADS 8
#define DH_DIM  16
#define DFF     512

__device__ __forceinline__ float lrelu(float v) { return v > 0.f ? v : 0.01f * v; }

// ---------------- zero counts ----------------
__global__ void k_zero(int* __restrict__ counts) {
    int i = blockIdx.x * 256 + threadIdx.x;
    if (i < N_NODES) counts[i] = 0;
}

// ---------------- count in-degree ----------------
__global__ void k_count(const int* __restrict__ ed, int* __restrict__ counts) {
    int e = blockIdx.x * 256 + threadIdx.x;
    if (e < E_EDGES) atomicAdd(&counts[ed[e]], 1);
}

// ---------------- exclusive scan (1 block, 1024 threads) ----------------
__global__ __launch_bounds__(1024) void k_scan(const int* __restrict__ counts,
                                               int* __restrict__ csr_off,
                                               int* __restrict__ cursor) {
    __shared__ int part[1024];
    const int CH = 49;  // 1024*49 = 50176 >= N
    int t = threadIdx.x;
    int base = t * CH;
    int s = 0;
    for (int k = 0; k < CH; ++k) {
        int idx = base + k;
        if (idx < N_NODES) s += counts[idx];
    }
    part[t] = s;
    __syncthreads();
    // inclusive scan over partials
    for (int off = 1; off < 1024; off <<= 1) {
        int v = (t >= off) ? part[t - off] : 0;
        __syncthreads();
        part[t] += v;
        __syncthreads();
    }
    int run = (t == 0) ? 0 : part[t - 1];
    for (int k = 0; k < CH; ++k) {
        int idx = base + k;
        if (idx < N_NODES) {
            csr_off[idx] = run;
            cursor[idx] = run;
            run += counts[idx];
        }
    }
    if (t == 0) csr_off[N_NODES] = E_EDGES;
}

// ---------------- fill CSR with src ids ----------------
__global__ void k_fill(const int* __restrict__ es, const int* __restrict__ ed,
                       int* __restrict__ cursor, int* __restrict__ csr_src) {
    int e = blockIdx.x * 256 + threadIdx.x;
    if (e < E_EDGES) {
        int pos = atomicAdd(&cursor[ed[e]], 1);
        csr_src[pos] = es[e];
    }
}

// ---------------- z = x @ Wp  (Wp[d][c] = W_fc[c>>4][d][c&15]) ----------------
__global__ __launch_bounds__(512) void k_proj(const float* __restrict__ x,
                                              const float* __restrict__ Wfc,
                                              float* __restrict__ z) {
    __shared__ float xT[128 * 68];   // xT[d][r], stride 68
    __shared__ float Wp[128 * 132];  // Wp[d][c], stride 132
    int t = threadIdx.x;
    int r0 = blockIdx.x * 64;
    for (int lin = t; lin < 64 * 128; lin += 512) {
        int r = lin >> 7, d = lin & 127;
        float v = 0.f;
        if (r0 + r < N_NODES) v = x[(r0 + r) * 128 + d];
        xT[d * 68 + r] = v;
    }
    for (int lin = t; lin < 4096; lin += 512) {
        int d = lin >> 5;
        int rem = lin & 31;
        int h = rem >> 2, q = (rem & 3) * 4;
        float4 w = *(const float4*)(Wfc + h * 2048 + d * 16 + q);
        *(float4*)&Wp[d * 132 + h * 16 + q] = w;
    }
    __syncthreads();
    int ct = t & 31, rt = t >> 5;
    int c0 = ct * 4, rr = rt * 4;
    float acc[4][4] = {};
    #pragma unroll 4
    for (int d = 0; d < 128; ++d) {
        float4 xv = *(const float4*)&xT[d * 68 + rr];
        float4 wv = *(const float4*)&Wp[d * 132 + c0];
        float xa[4] = {xv.x, xv.y, xv.z, xv.w};
        float wa[4] = {wv.x, wv.y, wv.z, wv.w};
        #pragma unroll
        for (int i = 0; i < 4; ++i)
            #pragma unroll
            for (int j = 0; j < 4; ++j) acc[i][j] += xa[i] * wa[j];
    }
    #pragma unroll
    for (int i = 0; i < 4; ++i) {
        int r = r0 + rr + i;
        if (r < N_NODES)
            *(float4*)&z[r * 128 + c0] =
                make_float4(acc[i][0], acc[i][1], acc[i][2], acc[i][3]);
    }
}

// ---------------- el/er ----------------
__global__ void k_el_er(const float* __restrict__ z, const float* __restrict__ a_l,
                        const float* __restrict__ a_r, float* __restrict__ el,
                        float* __restrict__ er) {
    int i = blockIdx.x * 256 + threadIdx.x;  // n*8 + h
    if (i >= N_NODES * H_HEADS) return;
    int h = i & 7;
    const float* zp = z + (size_t)(i >> 3) * 128 + h * 16;
    float sl = 0.f, sr = 0.f;
    #pragma unroll
    for (int k = 0; k < 16; ++k) {
        float v = zp[k];
        sl += v * a_l[h * 16 + k];
        sr += v * a_r[h * 16 + k];
    }
    el[i] = sl;
    er[i] = sr;
}

// ---------------- fused per-node softmax + aggregate (wave per node) --------
// lane = h*8 + s  (h = lane>>3 head, s = lane&7 edge slot)
__global__ __launch_bounds__(256) void k_node(const int* __restrict__ csr_off,
                                              const int* __restrict__ csr_src,
                                              const float* __restrict__ el,
                                              const float* __restrict__ er,
                                              const float* __restrict__ z,
                                              float* __restrict__ out) {
    int n = blockIdx.x * 4 + (threadIdx.x >> 6);
    if (n >= N_NODES) return;
    int lane = threadIdx.x & 63;
    int h = lane >> 3, s = lane & 7;
    int row = csr_off[n];
    int deg = csr_off[n + 1] - row;
    if (deg == 0) {
        *(float2*)&out[(size_t)n * 128 + lane * 2] = make_float2(0.f, 0.f);
        return;
    }
    float erv = er[n * 8 + h];
    int nch = (deg + 7) >> 3;

    // pass 1: compute e per (edge-slot, head), track running max
    float ev[8];
    int srcv[8];
    float mx = -INFINITY;
    for (int c = 0; c < nch; ++c) {
        int k = c * 8 + s;
        int src = 0;
        float e = -INFINITY;
        if (k < deg) {
            src = csr_src[row + k];
            e = lrelu(el[src * 8 + h] + erv);
        }
        if (c < 8) { ev[c] = e; srcv[c] = src; }
        mx = fmaxf(mx, e);
    }
    // per-head max over edge slots (lanes differing in bits 0..2)
    mx = fmaxf(mx, __shfl_xor(mx, 1));
    mx = fmaxf(mx, __shfl_xor(mx, 2));
    mx = fmaxf(mx, __shfl_xor(mx, 4));

    // pass 2: exp, sum, and unnormalized accumulate
    float ps = 0.f;
    float2 acc = make_float2(0.f, 0.f);
    int hj = lane >> 3;  // head owning output dims 2*lane, 2*lane+1... (below)
    // NOTE: output dims for this lane are 2*lane, 2*lane+1 -> head = (2*lane)/16 = lane>>3
    for (int c = 0; c < nch; ++c) {
        int k = c * 8 + s;
        float e;
        int src;
        if (c < 8) {
            e = ev[c]; src = srcv[c];
        } else {
            src = 0; e = -INFINITY;
            if (k < deg) {
                src = csr_src[row + k];
                e = lrelu(el[src * 8 + h] + erv);
            }
        }
        float p = (k < deg) ? __expf(e - mx) : 0.f;
        ps += p;
        int lim = min(8, deg - c * 8);
        for (int tt = 0; tt < lim; ++tt) {
            float a = __shfl(p, hj * 8 + tt);   // p of (edge tt, head hj)
            int se = __shfl(src, tt);            // src of edge tt (lane h=0,s=tt)
            float2 zv = *(const float2*)&z[(size_t)se * 128 + lane * 2];
            acc.x += a * zv.x;
            acc.y += a * zv.y;
        }
    }
    // per-head sum over edge slots
    ps += __shfl_xor(ps, 1);
    ps += __shfl_xor(ps, 2);
    ps += __shfl_xor(ps, 4);
    // total for head hj lives in lane hj*8 + 0
    float sumh = __shfl(ps, hj * 8);
    float inv = 1.f / fmaxf(sumh, 1e-9f);
    *(float2*)&out[(size_t)n * 128 + lane * 2] = make_float2(acc.x * inv, acc.y * inv);
}

// ---------------- fused elu+residual+LN+FFN ----------------
__global__ __launch_bounds__(512) void k_ffn(const float* __restrict__ x,
                                             const float* __restrict__ gamma,
                                             const float* __restrict__ beta,
                                             const float* __restrict__ W1,
                                             const float* __restrict__ b1,
                                             const float* __restrict__ W2,
                                             const float* __restrict__ b2,
                                             float* __restrict__ out) {
    __shared__ float uni[8704];     // hb[64][136] -> lnT[128][68]
    __shared__ float WL[128 * 132];
    __shared__ float interT[128 * 68];
    __shared__ float muL[64], rsL[64];
    int t = threadIdx.x;
    int r0 = blockIdx.x * 64;

    for (int lin = t; lin < 64 * 128; lin += 512) {
        int r = lin >> 7, d = lin & 127;
        float v = 0.f;
        int gr = r0 + r;
        if (gr < N_NODES) {
            float g = out[(size_t)gr * 128 + d];
            g = g > 0.f ? g : expm1f(g);
            v = x[(size_t)gr * 128 + d] + g;
        }
        uni[r * 136 + d] = v;
    }
    __syncthreads();
    {
        int r = t >> 3, j = t & 7;
        float sm = 0.f, sq = 0.f;
        for (int d = j; d < 128; d += 8) {
            float v = uni[r * 136 + d];
            sm += v; sq += v * v;
        }
        sm += __shfl_xor(sm, 1); sq += __shfl_xor(sq, 1);
        sm += __shfl_xor(sm, 2); sq += __shfl_xor(sq, 2);
        sm += __shfl_xor(sm, 4); sq += __shfl_xor(sq, 4);
        if (j == 0) {
            float mu = sm * (1.f / 128.f);
            float var = sq * (1.f / 128.f) - mu * mu;
            muL[r] = mu;
            rsL[r] = rsqrtf(var + 1e-5f);
        }
    }
    __syncthreads();
    float lnv[16];
    #pragma unroll
    for (int k = 0; k < 16; ++k) {
        int lin = t + k * 512;
        int r = lin >> 7, d = lin & 127;
        lnv[k] = (uni[r * 136 + d] - muL[r]) * rsL[r] * gamma[d] + beta[d];
    }
    __syncthreads();
    #pragma unroll
    for (int k = 0; k < 16; ++k) {
        int lin = t + k * 512;
        int r = lin >> 7, d = lin & 127;
        uni[d * 68 + r] = lnv[k];
    }
    __syncthreads();

    int ct = t & 31, rt = t >> 5;
    int c0 = ct * 4, rr = rt * 4;
    float oacc[4][4] = {};
    for (int tile = 0; tile < 4; ++tile) {
        int f0 = tile * 128;
        for (int lin = t; lin < 128 * 32; lin += 512) {
            int d = lin >> 5, q = (lin & 31) * 4;
            *(float4*)&WL[d * 132 + q] = *(const float4*)&W1[(size_t)d * 512 + f0 + q];
        }
        __syncthreads();
        float iacc[4][4] = {};
        #pragma unroll 4
        for (int d = 0; d < 128; ++d) {
            float4 lv = *(const float4*)&uni[d * 68 + rr];
            float4 wv = *(const float4*)&WL[d * 132 + c0];
            float la[4] = {lv.x, lv.y, lv.z, lv.w};
            float wa[4] = {wv.x, wv.y, wv.z, wv.w};
            #pragma unroll
            for (int ri = 0; ri < 4; ++ri)
                #pragma unroll
                for (int ci = 0; ci < 4; ++ci) iacc[ri][ci] += la[ri] * wa[ci];
        }
        #pragma unroll
        for (int fi = 0; fi < 4; ++fi) {
            float bb = b1[f0 + c0 + fi];
            #pragma unroll
            for (int ri = 0; ri < 4; ++ri) {
                float v = iacc[ri][fi] + bb;
                interT[(c0 + fi) * 68 + rr + ri] = v > 0.f ? v : 0.f;
            }
        }
        __syncthreads();
        for (int lin = t; lin < 128 * 32; lin += 512) {
            int fl = lin >> 5, q = (lin & 31) * 4;
            *(float4*)&WL[fl * 132 + q] = *(const float4*)&W2[(size_t)(f0 + fl) * 128 + q];
        }
        __syncthreads();
        #pragma unroll 4
        for (int fl = 0; fl < 128; ++fl) {
            float4 iv = *(const float4*)&interT[fl * 68 + rr];
            float4 wv = *(const float4*)&WL[fl * 132 + c0];
            float ia[4] = {iv.x, iv.y, iv.z, iv.w};
            float wa[4] = {wv.x, wv.y, wv.z, wv.w};
            #pragma unroll
            for (int ri = 0; ri < 4; ++ri)
                #pragma unroll
                for (int ci = 0; ci < 4; ++ci) oacc[ri][ci] += ia[ri] * wa[ci];
        }
        __syncthreads();
    }
    float4 b2v = *(const float4*)&b2[c0];
    float ba[4] = {b2v.x, b2v.y, b2v.z, b2v.w};
    #pragma unroll
    for (int ri = 0; ri < 4; ++ri) {
        int gr = r0 + rr + ri;
        if (gr < N_NODES) {
            float4 gv = *(const float4*)&out[(size_t)gr * 128 + c0];
            float4 xv = *(const float4*)&x[(size_t)gr * 128 + c0];
            float ga[4] = {gv.x, gv.y, gv.z, gv.w};
            float xa[4] = {xv.x, xv.y, xv.z, xv.w};
            float o[4];
            #pragma unroll
            for (int ci = 0; ci < 4; ++ci) {
                float g = ga[ci] > 0.f ? ga[ci] : expm1f(ga[ci]);
                o[ci] = oacc[ri][ci] + ba[ci] + xa[ci] + g;
            }
            *(float4*)&out[(size_t)gr * 128 + c0] = make_float4(o[0], o[1], o[2], o[3]);
        }
    }
}

extern "C" void kernel_launch(void* const* d_in, const int* in_sizes, int n_in,
                              void* d_out, int out_size, void* d_ws, size_t ws_size,
                              hipStream_t stream) {
    const float* x     = (const float*)d_in[0];
    const float* Wfc   = (const float*)d_in[1];
    const float* a_l   = (const float*)d_in[2];
    const float* a_r   = (const float*)d_in[3];
    const float* gamma = (const float*)d_in[4];
    const float* beta  = (const float*)d_in[5];
    const float* W1    = (const float*)d_in[6];
    const float* b1    = (const float*)d_in[7];
    const float* W2    = (const float*)d_in[8];
    const float* b2    = (const float*)d_in[9];
    const int*   es    = (const int*)d_in[10];
    const int*   ed    = (const int*)d_in[11];
    float* out = (float*)d_out;

    float* ws = (float*)d_ws;
    float* z  = ws;                                   // N*128 f
    float* el = z + (size_t)N_NODES * 128;            // N*8
    float* er = el + N_NODES * 8;                     // N*8
    int* counts  = (int*)(er + N_NODES * 8);          // N
    int* csr_off = counts + N_NODES;                  // N+1
    int* cursor  = csr_off + N_NODES + 1;             // N
    int* csr_src = cursor + N_NODES + 1;              // E (pad for alignment)

    k_zero<<<dim3((N_NODES + 255) / 256), dim3(256), 0, stream>>>(counts);
    k_count<<<dim3((E_EDGES + 255) / 256), dim3(256), 0, stream>>>(ed, counts);
    k_scan<<<dim3(1), dim3(1024), 0, stream>>>(counts, csr_off, cursor);
    k_fill<<<dim3((E_EDGES + 255) / 256), dim3(256), 0, stream>>>(es, ed, cursor, csr_src);
    k_proj<<<dim3((N_NODES + 63) / 64), dim3(512), 0, stream>>>(x, Wfc, z);
    k_el_er<<<dim3((N_NODES * H_HEADS + 255) / 256), dim3(256), 0, stream>>>(z, a_l, a_r, el, er);
    k_node<<<dim3((N_NODES + 3) / 4), dim3(256), 0, stream>>>(csr_off, csr_src, el, er, z, out);
    k_ffn<<<dim3((N_NODES + 63) / 64), dim3(512), 0, stream>>>(x, gamma, beta, W1, b1, W2, b2, out);
}

// Round 3
// 416.603 us; speedup vs baseline: 3.9164x; 1.5549x over previous
//
#include <hip/hip_runtime.h>
#include <math.h>

#define N_NODES 50000
#define E_EDGES 800000
#define D_DIM   128
#define H_HEADS 8
#define DH_DIM  16
#define DFF     512

typedef __bf16 bf16_t;
typedef bf16_t bf16x8 __attribute__((ext_vector_type(8)));
typedef float f32x4 __attribute__((ext_vector_type(4)));
typedef unsigned short u16x8 __attribute__((ext_vector_type(8)));

#define SWZ(r) (((r) & 7) << 4)

__device__ __forceinline__ float lrelu(float v) { return v > 0.f ? v : 0.01f * v; }
__device__ __forceinline__ unsigned short f2b(float f) {
    unsigned u = __float_as_uint(f);
    unsigned r = (u + 0x7FFFu + ((u >> 16) & 1u)) >> 16;
    return (unsigned short)r;
}

// ---------------- zero counts ----------------
__global__ void k_zero(int* __restrict__ counts) {
    int i = blockIdx.x * 256 + threadIdx.x;
    if (i < N_NODES) counts[i] = 0;
}

// ---------------- count in-degree ----------------
__global__ void k_count(const int* __restrict__ ed, int* __restrict__ counts) {
    int e = blockIdx.x * 256 + threadIdx.x;
    if (e < E_EDGES) atomicAdd(&counts[ed[e]], 1);
}

// ---------------- exclusive scan (1 block, 1024 threads) ----------------
__global__ __launch_bounds__(1024) void k_scan(const int* __restrict__ counts,
                                               int* __restrict__ csr_off,
                                               int* __restrict__ cursor) {
    __shared__ int part[1024];
    const int CH = 49;
    int t = threadIdx.x;
    int base = t * CH;
    int s = 0;
    for (int k = 0; k < CH; ++k) {
        int idx = base + k;
        if (idx < N_NODES) s += counts[idx];
    }
    part[t] = s;
    __syncthreads();
    for (int off = 1; off < 1024; off <<= 1) {
        int v = (t >= off) ? part[t - off] : 0;
        __syncthreads();
        part[t] += v;
        __syncthreads();
    }
    int run = (t == 0) ? 0 : part[t - 1];
    for (int k = 0; k < CH; ++k) {
        int idx = base + k;
        if (idx < N_NODES) {
            csr_off[idx] = run;
            cursor[idx] = run;
            run += counts[idx];
        }
    }
    if (t == 0) csr_off[N_NODES] = E_EDGES;
}

// ---------------- fill CSR with src ids ----------------
__global__ void k_fill(const int* __restrict__ es, const int* __restrict__ ed,
                       int* __restrict__ cursor, int* __restrict__ csr_src) {
    int e = blockIdx.x * 256 + threadIdx.x;
    if (e < E_EDGES) {
        int pos = atomicAdd(&cursor[ed[e]], 1);
        csr_src[pos] = es[e];
    }
}

// ---------------- weight prep: transpose + bf16 ----------------
__global__ void k_prep(const float* __restrict__ W1, const float* __restrict__ W2,
                       bf16_t* __restrict__ W1T, bf16_t* __restrict__ W2T) {
    int id = blockIdx.x * 256 + threadIdx.x;
    if (id < 512 * 128) {
        int c = id >> 7, k = id & 127;
        W1T[id] = (bf16_t)W1[(size_t)k * 512 + c];
        int c2 = id >> 9, k2 = id & 511;
        W2T[id] = (bf16_t)W2[(size_t)k2 * 128 + c2];
    }
}

// ---------------- z = x @ Wp ----------------
__global__ __launch_bounds__(512) void k_proj(const float* __restrict__ x,
                                              const float* __restrict__ Wfc,
                                              float* __restrict__ z) {
    __shared__ float xT[128 * 68];
    __shared__ float Wp[128 * 132];
    int t = threadIdx.x;
    int r0 = blockIdx.x * 64;
    for (int lin = t; lin < 64 * 128; lin += 512) {
        int r = lin >> 7, d = lin & 127;
        float v = 0.f;
        if (r0 + r < N_NODES) v = x[(r0 + r) * 128 + d];
        xT[d * 68 + r] = v;
    }
    for (int lin = t; lin < 4096; lin += 512) {
        int d = lin >> 5;
        int rem = lin & 31;
        int h = rem >> 2, q = (rem & 3) * 4;
        float4 w = *(const float4*)(Wfc + h * 2048 + d * 16 + q);
        *(float4*)&Wp[d * 132 + h * 16 + q] = w;
    }
    __syncthreads();
    int ct = t & 31, rt = t >> 5;
    int c0 = ct * 4, rr = rt * 4;
    float acc[4][4] = {};
    #pragma unroll 4
    for (int d = 0; d < 128; ++d) {
        float4 xv = *(const float4*)&xT[d * 68 + rr];
        float4 wv = *(const float4*)&Wp[d * 132 + c0];
        float xa[4] = {xv.x, xv.y, xv.z, xv.w};
        float wa[4] = {wv.x, wv.y, wv.z, wv.w};
        #pragma unroll
        for (int i = 0; i < 4; ++i)
            #pragma unroll
            for (int j = 0; j < 4; ++j) acc[i][j] += xa[i] * wa[j];
    }
    #pragma unroll
    for (int i = 0; i < 4; ++i) {
        int r = r0 + rr + i;
        if (r < N_NODES)
            *(float4*)&z[r * 128 + c0] =
                make_float4(acc[i][0], acc[i][1], acc[i][2], acc[i][3]);
    }
}

// ---------------- el/er ----------------
__global__ void k_el_er(const float* __restrict__ z, const float* __restrict__ a_l,
                        const float* __restrict__ a_r, float* __restrict__ el,
                        float* __restrict__ er) {
    int i = blockIdx.x * 256 + threadIdx.x;
    if (i >= N_NODES * H_HEADS) return;
    int h = i & 7;
    const float* zp = z + (size_t)(i >> 3) * 128 + h * 16;
    float sl = 0.f, sr = 0.f;
    #pragma unroll
    for (int k = 0; k < 16; ++k) {
        float v = zp[k];
        sl += v * a_l[h * 16 + k];
        sr += v * a_r[h * 16 + k];
    }
    el[i] = sl;
    er[i] = sr;
}

// ---------------- fused per-node softmax + aggregate (wave per node) --------
__global__ __launch_bounds__(256) void k_node(const int* __restrict__ csr_off,
                                              const int* __restrict__ csr_src,
                                              const float* __restrict__ el,
                                              const float* __restrict__ er,
                                              const float* __restrict__ z,
                                              float* __restrict__ out) {
    int n = blockIdx.x * 4 + (threadIdx.x >> 6);
    if (n >= N_NODES) return;
    int lane = threadIdx.x & 63;
    int h = lane >> 3, s = lane & 7;
    int row = csr_off[n];
    int deg = csr_off[n + 1] - row;
    if (deg == 0) {
        *(float2*)&out[(size_t)n * 128 + lane * 2] = make_float2(0.f, 0.f);
        return;
    }
    float erv = er[n * 8 + h];
    int nch = (deg + 7) >> 3;

    float ev[8];
    int srcv[8];
    float mx = -INFINITY;
    for (int c = 0; c < nch; ++c) {
        int k = c * 8 + s;
        int src = 0;
        float e = -INFINITY;
        if (k < deg) {
            src = csr_src[row + k];
            e = lrelu(el[src * 8 + h] + erv);
        }
        if (c < 8) { ev[c] = e; srcv[c] = src; }
        mx = fmaxf(mx, e);
    }
    mx = fmaxf(mx, __shfl_xor(mx, 1));
    mx = fmaxf(mx, __shfl_xor(mx, 2));
    mx = fmaxf(mx, __shfl_xor(mx, 4));

    float ps = 0.f;
    float2 acc = make_float2(0.f, 0.f);
    int hj = lane >> 3;
    for (int c = 0; c < nch; ++c) {
        int k = c * 8 + s;
        float e;
        int src;
        if (c < 8) {
            e = ev[c]; src = srcv[c];
        } else {
            src = 0; e = -INFINITY;
            if (k < deg) {
                src = csr_src[row + k];
                e = lrelu(el[src * 8 + h] + erv);
            }
        }
        float p = (k < deg) ? __expf(e - mx) : 0.f;
        ps += p;
        int lim = min(8, deg - c * 8);
        for (int tt = 0; tt < lim; ++tt) {
            float a = __shfl(p, hj * 8 + tt);
            int se = __shfl(src, tt);
            float2 zv = *(const float2*)&z[(size_t)se * 128 + lane * 2];
            acc.x += a * zv.x;
            acc.y += a * zv.y;
        }
    }
    ps += __shfl_xor(ps, 1);
    ps += __shfl_xor(ps, 2);
    ps += __shfl_xor(ps, 4);
    float sumh = __shfl(ps, hj * 8);
    float inv = 1.f / fmaxf(sumh, 1e-9f);
    *(float2*)&out[(size_t)n * 128 + lane * 2] = make_float2(acc.x * inv, acc.y * inv);
}

// ---------------- fused elu+residual+LN+FFN with bf16 MFMA ----------------
// 64 rows/block, 512 threads (8 waves). LDS: lnA 16KB + inA 64KB = 80KB (2 blk/CU)
__global__ __launch_bounds__(512, 4) void k_ffn(const float* __restrict__ x,
                                                const float* __restrict__ gamma,
                                                const float* __restrict__ beta,
                                                const bf16_t* __restrict__ W1T,
                                                const float* __restrict__ b1,
                                                const bf16_t* __restrict__ W2T,
                                                const float* __restrict__ b2,
                                                float* __restrict__ out) {
    __shared__ char smem[81920];
    char* lnA = smem;           // bf16[64][128], row stride 256B, XOR-swizzled
    char* inA = smem + 16384;   // bf16[64][512], row stride 1024B, XOR-swizzled
    int t = threadIdx.x;
    int r0 = blockIdx.x * 64;

    // phase 0: h = x + elu(gat); LN in registers; ln -> lnA (bf16, swizzled)
    {
        int r = t >> 3, c0 = (t & 7) * 16;
        int gr = r0 + r;
        float hv[16];
        if (gr < N_NODES) {
            #pragma unroll
            for (int q = 0; q < 4; ++q) {
                float4 g4 = *(const float4*)&out[(size_t)gr * 128 + c0 + q * 4];
                float4 x4 = *(const float4*)&x[(size_t)gr * 128 + c0 + q * 4];
                float ga[4] = {g4.x, g4.y, g4.z, g4.w};
                float xa[4] = {x4.x, x4.y, x4.z, x4.w};
                #pragma unroll
                for (int i = 0; i < 4; ++i) {
                    float g = ga[i] > 0.f ? ga[i] : expm1f(ga[i]);
                    hv[q * 4 + i] = xa[i] + g;
                }
            }
        } else {
            #pragma unroll
            for (int i = 0; i < 16; ++i) hv[i] = 0.f;
        }
        float sm = 0.f, sq = 0.f;
        #pragma unroll
        for (int i = 0; i < 16; ++i) { sm += hv[i]; sq += hv[i] * hv[i]; }
        sm += __shfl_xor(sm, 1); sq += __shfl_xor(sq, 1);
        sm += __shfl_xor(sm, 2); sq += __shfl_xor(sq, 2);
        sm += __shfl_xor(sm, 4); sq += __shfl_xor(sq, 4);
        float mu = sm * (1.f / 128.f);
        float rs = rsqrtf(sq * (1.f / 128.f) - mu * mu + 1e-5f);
        u16x8 pk0, pk1;
        #pragma unroll
        for (int i = 0; i < 8; ++i) {
            pk0[i] = f2b((hv[i] - mu) * rs * gamma[c0 + i] + beta[c0 + i]);
            pk1[i] = f2b((hv[8 + i] - mu) * rs * gamma[c0 + 8 + i] + beta[c0 + 8 + i]);
        }
        int base = r * 256 + c0 * 2;
        *(u16x8*)(lnA + (base ^ SWZ(r))) = pk0;
        *(u16x8*)(lnA + ((base + 16) ^ SWZ(r))) = pk1;
    }
    __syncthreads();

    int wv = t >> 6, l = t & 63;
    int lr = l & 15, lg = l >> 4;

    // GEMM1: inter[64][512] = relu(ln @ W1 + b1); wave wv covers cols [wv*64, wv*64+64)
    {
        int n0 = wv * 64;
        f32x4 acc[4][4] = {};
        #pragma unroll
        for (int ks = 0; ks < 4; ++ks) {
            bf16x8 a[4], b[4];
            #pragma unroll
            for (int mi = 0; mi < 4; ++mi) {
                int row = mi * 16 + lr;
                int off = (row * 256 + ks * 64 + lg * 16) ^ SWZ(row);
                a[mi] = *(const bf16x8*)(lnA + off);
            }
            #pragma unroll
            for (int ni = 0; ni < 4; ++ni) {
                int c = n0 + ni * 16 + lr;
                b[ni] = *(const bf16x8*)(W1T + (size_t)c * 128 + ks * 32 + lg * 8);
            }
            #pragma unroll
            for (int mi = 0; mi < 4; ++mi)
                #pragma unroll
                for (int ni = 0; ni < 4; ++ni)
                    acc[mi][ni] = __builtin_amdgcn_mfma_f32_16x16x32_bf16(
                        a[mi], b[ni], acc[mi][ni], 0, 0, 0);
        }
        // bias + relu -> inA (bf16, swizzled); D layout: col=lr, row=lg*4+reg
        #pragma unroll
        for (int ni = 0; ni < 4; ++ni) {
            int c = n0 + ni * 16 + lr;
            float bb = b1[c];
            #pragma unroll
            for (int mi = 0; mi < 4; ++mi) {
                #pragma unroll
                for (int rg = 0; rg < 4; ++rg) {
                    int row = mi * 16 + lg * 4 + rg;
                    float v = acc[mi][ni][rg] + bb;
                    v = v > 0.f ? v : 0.f;
                    *(unsigned short*)(inA + ((row * 1024 + c * 2) ^ SWZ(row))) = f2b(v);
                }
            }
        }
    }
    __syncthreads();

    // GEMM2: out2[64][128] = inter @ W2 + b2; wave wv covers cols [wv*16, wv*16+16)
    {
        int n2 = wv * 16;
        f32x4 acc2[4] = {};
        #pragma unroll
        for (int ks = 0; ks < 16; ++ks) {
            bf16x8 bfr = *(const bf16x8*)(W2T + (size_t)(n2 + lr) * 512 + ks * 32 + lg * 8);
            #pragma unroll
            for (int mi = 0; mi < 4; ++mi) {
                int row = mi * 16 + lr;
                int off = (row * 1024 + ks * 64 + lg * 16) ^ SWZ(row);
                bf16x8 a2 = *(const bf16x8*)(inA + off);
                acc2[mi] = __builtin_amdgcn_mfma_f32_16x16x32_bf16(a2, bfr, acc2[mi], 0, 0, 0);
            }
        }
        float bb2 = b2[n2 + lr];
        #pragma unroll
        for (int mi = 0; mi < 4; ++mi) {
            #pragma unroll
            for (int rg = 0; rg < 4; ++rg) {
                int row = mi * 16 + lg * 4 + rg;
                int gr = r0 + row;
                if (gr < N_NODES) {
                    size_t idx = (size_t)gr * 128 + n2 + lr;
                    float g = out[idx];
                    g = g > 0.f ? g : expm1f(g);
                    out[idx] = acc2[mi][rg] + bb2 + x[idx] + g;
                }
            }
        }
    }
}

extern "C" void kernel_launch(void* const* d_in, const int* in_sizes, int n_in,
                              void* d_out, int out_size, void* d_ws, size_t ws_size,
                              hipStream_t stream) {
    const float* x     = (const float*)d_in[0];
    const float* Wfc   = (const float*)d_in[1];
    const float* a_l   = (const float*)d_in[2];
    const float* a_r   = (const float*)d_in[3];
    const float* gamma = (const float*)d_in[4];
    const float* beta  = (const float*)d_in[5];
    const float* W1    = (const float*)d_in[6];
    const float* b1    = (const float*)d_in[7];
    const float* W2    = (const float*)d_in[8];
    const float* b2    = (const float*)d_in[9];
    const int*   es    = (const int*)d_in[10];
    const int*   ed    = (const int*)d_in[11];
    float* out = (float*)d_out;

    bf16_t* W1T = (bf16_t*)d_ws;              // 512*128
    bf16_t* W2T = W1T + 512 * 128;            // 128*512
    float* z  = (float*)(W2T + 128 * 512);    // N*128
    float* el = z + (size_t)N_NODES * 128;    // N*8
    float* er = el + N_NODES * 8;             // N*8
    int* counts  = (int*)(er + N_NODES * 8);  // N
    int* csr_off = counts + N_NODES;          // N+1
    int* cursor  = csr_off + N_NODES + 1;     // N+1
    int* csr_src = cursor + N_NODES + 1;      // E

    k_zero<<<dim3((N_NODES + 255) / 256), dim3(256), 0, stream>>>(counts);
    k_count<<<dim3((E_EDGES + 255) / 256), dim3(256), 0, stream>>>(ed, counts);
    k_scan<<<dim3(1), dim3(1024), 0, stream>>>(counts, csr_off, cursor);
    k_fill<<<dim3((E_EDGES + 255) / 256), dim3(256), 0, stream>>>(es, ed, cursor, csr_src);
    k_prep<<<dim3(256), dim3(256), 0, stream>>>(W1, W2, W1T, W2T);
    k_proj<<<dim3((N_NODES + 63) / 64), dim3(512), 0, stream>>>(x, Wfc, z);
    k_el_er<<<dim3((N_NODES * H_HEADS + 255) / 256), dim3(256), 0, stream>>>(z, a_l, a_r, el, er);
    k_node<<<dim3((N_NODES + 3) / 4), dim3(256), 0, stream>>>(csr_off, csr_src, el, er, z, out);
    k_ffn<<<dim3((N_NODES + 63) / 64), dim3(512), 0, stream>>>(x, gamma, beta, W1T, b1, W2T, b2, out);
}

// Round 4
// 300.834 us; speedup vs baseline: 5.4236x; 1.3848x over previous
//
#include <hip/hip_runtime.h>
#include <math.h>

#define N_NODES 50000
#define E_EDGES 800000
#define D_DIM   128
#define H_HEADS 8
#define DH_DIM  16
#define DFF     512

#define SCAN_BLOCKS 98  // 98*512 = 50176 >= N_NODES+1

typedef __bf16 bf16_t;
typedef bf16_t bf16x8 __attribute__((ext_vector_type(8)));
typedef float f32x4 __attribute__((ext_vector_type(4)));
typedef unsigned short u16x8 __attribute__((ext_vector_type(8)));

#define SWZ(r) (((r) & 7) << 4)

__device__ __forceinline__ float lrelu(float v) { return v > 0.f ? v : 0.01f * v; }
__device__ __forceinline__ unsigned short f2b(float f) {
    unsigned u = __float_as_uint(f);
    unsigned r = (u + 0x7FFFu + ((u >> 16) & 1u)) >> 16;
    return (unsigned short)r;
}

// ---------------- zero counts ----------------
__global__ void k_zero(int* __restrict__ counts) {
    int i = blockIdx.x * 256 + threadIdx.x;
    if (i < N_NODES) counts[i] = 0;
}

// ---------------- count in-degree ----------------
__global__ void k_count(const int* __restrict__ ed, int* __restrict__ counts) {
    int e = blockIdx.x * 256 + threadIdx.x;
    if (e < E_EDGES) atomicAdd(&counts[ed[e]], 1);
}

// ---------------- hierarchical scan ----------------
__global__ __launch_bounds__(512) void k_scan1(const int* __restrict__ counts,
                                               int* __restrict__ bsum) {
    int i = blockIdx.x * 512 + threadIdx.x;
    int v = (i < N_NODES) ? counts[i] : 0;
    #pragma unroll
    for (int o = 1; o < 64; o <<= 1) v += __shfl_xor(v, o);
    __shared__ int ws[8];
    if ((threadIdx.x & 63) == 0) ws[threadIdx.x >> 6] = v;
    __syncthreads();
    if (threadIdx.x == 0) {
        int s = 0;
        #pragma unroll
        for (int k = 0; k < 8; ++k) s += ws[k];
        bsum[blockIdx.x] = s;
    }
}

__global__ __launch_bounds__(128) void k_scan2(const int* __restrict__ bsum,
                                               int* __restrict__ boff) {
    __shared__ int tmp[128];
    int t = threadIdx.x;
    int v = (t < SCAN_BLOCKS) ? bsum[t] : 0;
    tmp[t] = v;
    __syncthreads();
    for (int o = 1; o < 128; o <<= 1) {
        int u = (t >= o) ? tmp[t - o] : 0;
        __syncthreads();
        tmp[t] += u;
        __syncthreads();
    }
    boff[t] = (t == 0) ? 0 : tmp[t - 1];
}

__global__ __launch_bounds__(512) void k_scan3(const int* __restrict__ counts,
                                               const int* __restrict__ boff,
                                               int* __restrict__ csr_off,
                                               int* __restrict__ cursor) {
    int t = threadIdx.x;
    int i = blockIdx.x * 512 + t;
    int v = (i < N_NODES) ? counts[i] : 0;
    int lane = t & 63, w = t >> 6;
    int xs = v;
    #pragma unroll
    for (int o = 1; o < 64; o <<= 1) {
        int u = __shfl_up(xs, o);
        if (lane >= o) xs += u;
    }
    __shared__ int ws[8];
    __shared__ int wo[8];
    if (lane == 63) ws[w] = xs;
    __syncthreads();
    if (t == 0) {
        int s = 0;
        #pragma unroll
        for (int k = 0; k < 8; ++k) { wo[k] = s; s += ws[k]; }
    }
    __syncthreads();
    int excl = xs - v + wo[w] + boff[blockIdx.x];
    if (i < N_NODES) { csr_off[i] = excl; cursor[i] = excl; }
    if (i == N_NODES) csr_off[N_NODES] = E_EDGES;
}

// ---------------- fill CSR with src ids ----------------
__global__ void k_fill(const int* __restrict__ es, const int* __restrict__ ed,
                       int* __restrict__ cursor, int* __restrict__ csr_src) {
    int e = blockIdx.x * 256 + threadIdx.x;
    if (e < E_EDGES) {
        int pos = atomicAdd(&cursor[ed[e]], 1);
        csr_src[pos] = es[e];
    }
}

// ---------------- weight prep: transpose + bf16 ----------------
__global__ void k_prep(const float* __restrict__ W1, const float* __restrict__ W2,
                       bf16_t* __restrict__ W1T, bf16_t* __restrict__ W2T) {
    int id = blockIdx.x * 256 + threadIdx.x;
    if (id < 512 * 128) {
        int c = id >> 7, k = id & 127;
        W1T[id] = (bf16_t)W1[(size_t)k * 512 + c];
        int c2 = id >> 9, k2 = id & 511;
        W2T[id] = (bf16_t)W2[(size_t)k2 * 128 + c2];
    }
}

// ---------------- z = x @ Wp ----------------
__global__ __launch_bounds__(512) void k_proj(const float* __restrict__ x,
                                              const float* __restrict__ Wfc,
                                              float* __restrict__ z) {
    __shared__ float xT[128 * 68];
    __shared__ float Wp[128 * 132];
    int t = threadIdx.x;
    int r0 = blockIdx.x * 64;
    for (int lin = t; lin < 64 * 128; lin += 512) {
        int r = lin >> 7, d = lin & 127;
        float v = 0.f;
        if (r0 + r < N_NODES) v = x[(r0 + r) * 128 + d];
        xT[d * 68 + r] = v;
    }
    for (int lin = t; lin < 4096; lin += 512) {
        int d = lin >> 5;
        int rem = lin & 31;
        int h = rem >> 2, q = (rem & 3) * 4;
        float4 w = *(const float4*)(Wfc + h * 2048 + d * 16 + q);
        *(float4*)&Wp[d * 132 + h * 16 + q] = w;
    }
    __syncthreads();
    int ct = t & 31, rt = t >> 5;
    int c0 = ct * 4, rr = rt * 4;
    float acc[4][4] = {};
    #pragma unroll 4
    for (int d = 0; d < 128; ++d) {
        float4 xv = *(const float4*)&xT[d * 68 + rr];
        float4 wv = *(const float4*)&Wp[d * 132 + c0];
        float xa[4] = {xv.x, xv.y, xv.z, xv.w};
        float wa[4] = {wv.x, wv.y, wv.z, wv.w};
        #pragma unroll
        for (int i = 0; i < 4; ++i)
            #pragma unroll
            for (int j = 0; j < 4; ++j) acc[i][j] += xa[i] * wa[j];
    }
    #pragma unroll
    for (int i = 0; i < 4; ++i) {
        int r = r0 + rr + i;
        if (r < N_NODES)
            *(float4*)&z[r * 128 + c0] =
                make_float4(acc[i][0], acc[i][1], acc[i][2], acc[i][3]);
    }
}

// ---------------- el/er ----------------
__global__ void k_el_er(const float* __restrict__ z, const float* __restrict__ a_l,
                        const float* __restrict__ a_r, float* __restrict__ el,
                        float* __restrict__ er) {
    int i = blockIdx.x * 256 + threadIdx.x;
    if (i >= N_NODES * H_HEADS) return;
    int h = i & 7;
    const float* zp = z + (size_t)(i >> 3) * 128 + h * 16;
    float sl = 0.f, sr = 0.f;
    #pragma unroll
    for (int k = 0; k < 16; ++k) {
        float v = zp[k];
        sl += v * a_l[h * 16 + k];
        sr += v * a_r[h * 16 + k];
    }
    el[i] = sl;
    er[i] = sr;
}

// ---------------- fused per-node softmax + aggregate (wave per node) --------
__global__ __launch_bounds__(256) void k_node(const int* __restrict__ csr_off,
                                              const int* __restrict__ csr_src,
                                              const float* __restrict__ el,
                                              const float* __restrict__ er,
                                              const float* __restrict__ z,
                                              float* __restrict__ out) {
    int n = blockIdx.x * 4 + (threadIdx.x >> 6);
    if (n >= N_NODES) return;
    int lane = threadIdx.x & 63;
    int h = lane >> 3, s = lane & 7;
    int row = csr_off[n];
    int deg = csr_off[n + 1] - row;
    if (deg == 0) {
        *(float2*)&out[(size_t)n * 128 + lane * 2] = make_float2(0.f, 0.f);
        return;
    }
    float erv = er[n * 8 + h];
    int nch = (deg + 7) >> 3;

    float ev[8];
    int srcv[8];
    float mx = -INFINITY;
    for (int c = 0; c < nch; ++c) {
        int k = c * 8 + s;
        int src = 0;
        float e = -INFINITY;
        if (k < deg) {
            src = csr_src[row + k];
            e = lrelu(el[src * 8 + h] + erv);
        }
        if (c < 8) { ev[c] = e; srcv[c] = src; }
        mx = fmaxf(mx, e);
    }
    mx = fmaxf(mx, __shfl_xor(mx, 1));
    mx = fmaxf(mx, __shfl_xor(mx, 2));
    mx = fmaxf(mx, __shfl_xor(mx, 4));

    float ps = 0.f;
    float2 acc = make_float2(0.f, 0.f);
    int hj = lane >> 3;
    for (int c = 0; c < nch; ++c) {
        int k = c * 8 + s;
        float e;
        int src;
        if (c < 8) {
            e = ev[c]; src = srcv[c];
        } else {
            src = 0; e = -INFINITY;
            if (k < deg) {
                src = csr_src[row + k];
                e = lrelu(el[src * 8 + h] + erv);
            }
        }
        float p = (k < deg) ? __expf(e - mx) : 0.f;
        ps += p;
        int lim = min(8, deg - c * 8);
        for (int tt = 0; tt < lim; ++tt) {
            float a = __shfl(p, hj * 8 + tt);
            int se = __shfl(src, tt);
            float2 zv = *(const float2*)&z[(size_t)se * 128 + lane * 2];
            acc.x += a * zv.x;
            acc.y += a * zv.y;
        }
    }
    ps += __shfl_xor(ps, 1);
    ps += __shfl_xor(ps, 2);
    ps += __shfl_xor(ps, 4);
    float sumh = __shfl(ps, hj * 8);
    float inv = 1.f / fmaxf(sumh, 1e-9f);
    *(float2*)&out[(size_t)n * 128 + lane * 2] = make_float2(acc.x * inv, acc.y * inv);
}

// ---------------- fused elu+residual+LN+FFN with bf16 MFMA ----------------
__global__ __launch_bounds__(512, 4) void k_ffn(const float* __restrict__ x,
                                                const float* __restrict__ gamma,
                                                const float* __restrict__ beta,
                                                const bf16_t* __restrict__ W1T,
                                                const float* __restrict__ b1,
                                                const bf16_t* __restrict__ W2T,
                                                const float* __restrict__ b2,
                                                float* __restrict__ out) {
    __shared__ char smem[81920];
    char* lnA = smem;           // bf16[64][128], row stride 256B, XOR-swizzled
    char* inA = smem + 16384;   // bf16[64][512], row stride 1024B, XOR-swizzled
    int t = threadIdx.x;
    int r0 = blockIdx.x * 64;

    {
        int r = t >> 3, c0 = (t & 7) * 16;
        int gr = r0 + r;
        float hv[16];
        if (gr < N_NODES) {
            #pragma unroll
            for (int q = 0; q < 4; ++q) {
                float4 g4 = *(const float4*)&out[(size_t)gr * 128 + c0 + q * 4];
                float4 x4 = *(const float4*)&x[(size_t)gr * 128 + c0 + q * 4];
                float ga[4] = {g4.x, g4.y, g4.z, g4.w};
                float xa[4] = {x4.x, x4.y, x4.z, x4.w};
                #pragma unroll
                for (int i = 0; i < 4; ++i) {
                    float g = ga[i] > 0.f ? ga[i] : expm1f(ga[i]);
                    hv[q * 4 + i] = xa[i] + g;
                }
            }
        } else {
            #pragma unroll
            for (int i = 0; i < 16; ++i) hv[i] = 0.f;
        }
        float sm = 0.f, sq = 0.f;
        #pragma unroll
        for (int i = 0; i < 16; ++i) { sm += hv[i]; sq += hv[i] * hv[i]; }
        sm += __shfl_xor(sm, 1); sq += __shfl_xor(sq, 1);
        sm += __shfl_xor(sm, 2); sq += __shfl_xor(sq, 2);
        sm += __shfl_xor(sm, 4); sq += __shfl_xor(sq, 4);
        float mu = sm * (1.f / 128.f);
        float rs = rsqrtf(sq * (1.f / 128.f) - mu * mu + 1e-5f);
        u16x8 pk0, pk1;
        #pragma unroll
        for (int i = 0; i < 8; ++i) {
            pk0[i] = f2b((hv[i] - mu) * rs * gamma[c0 + i] + beta[c0 + i]);
            pk1[i] = f2b((hv[8 + i] - mu) * rs * gamma[c0 + 8 + i] + beta[c0 + 8 + i]);
        }
        int base = r * 256 + c0 * 2;
        *(u16x8*)(lnA + (base ^ SWZ(r))) = pk0;
        *(u16x8*)(lnA + ((base + 16) ^ SWZ(r))) = pk1;
    }
    __syncthreads();

    int wv = t >> 6, l = t & 63;
    int lr = l & 15, lg = l >> 4;

    {
        int n0 = wv * 64;
        f32x4 acc[4][4] = {};
        #pragma unroll
        for (int ks = 0; ks < 4; ++ks) {
            bf16x8 a[4], b[4];
            #pragma unroll
            for (int mi = 0; mi < 4; ++mi) {
                int row = mi * 16 + lr;
                int off = (row * 256 + ks * 64 + lg * 16) ^ SWZ(row);
                a[mi] = *(const bf16x8*)(lnA + off);
            }
            #pragma unroll
            for (int ni = 0; ni < 4; ++ni) {
                int c = n0 + ni * 16 + lr;
                b[ni] = *(const bf16x8*)(W1T + (size_t)c * 128 + ks * 32 + lg * 8);
            }
            #pragma unroll
            for (int mi = 0; mi < 4; ++mi)
                #pragma unroll
                for (int ni = 0; ni < 4; ++ni)
                    acc[mi][ni] = __builtin_amdgcn_mfma_f32_16x16x32_bf16(
                        a[mi], b[ni], acc[mi][ni], 0, 0, 0);
        }
        #pragma unroll
        for (int ni = 0; ni < 4; ++ni) {
            int c = n0 + ni * 16 + lr;
            float bb = b1[c];
            #pragma unroll
            for (int mi = 0; mi < 4; ++mi) {
                #pragma unroll
                for (int rg = 0; rg < 4; ++rg) {
                    int row = mi * 16 + lg * 4 + rg;
                    float v = acc[mi][ni][rg] + bb;
                    v = v > 0.f ? v : 0.f;
                    *(unsigned short*)(inA + ((row * 1024 + c * 2) ^ SWZ(row))) = f2b(v);
                }
            }
        }
    }
    __syncthreads();

    {
        int n2 = wv * 16;
        f32x4 acc2[4] = {};
        #pragma unroll
        for (int ks = 0; ks < 16; ++ks) {
            bf16x8 bfr = *(const bf16x8*)(W2T + (size_t)(n2 + lr) * 512 + ks * 32 + lg * 8);
            #pragma unroll
            for (int mi = 0; mi < 4; ++mi) {
                int row = mi * 16 + lr;
                int off = (row * 1024 + ks * 64 + lg * 16) ^ SWZ(row);
                bf16x8 a2 = *(const bf16x8*)(inA + off);
                acc2[mi] = __builtin_amdgcn_mfma_f32_16x16x32_bf16(a2, bfr, acc2[mi], 0, 0, 0);
            }
        }
        float bb2 = b2[n2 + lr];
        #pragma unroll
        for (int mi = 0; mi < 4; ++mi) {
            #pragma unroll
            for (int rg = 0; rg < 4; ++rg) {
                int row = mi * 16 + lg * 4 + rg;
                int gr = r0 + row;
                if (gr < N_NODES) {
                    size_t idx = (size_t)gr * 128 + n2 + lr;
                    float g = out[idx];
                    g = g > 0.f ? g : expm1f(g);
                    out[idx] = acc2[mi][rg] + bb2 + x[idx] + g;
                }
            }
        }
    }
}

extern "C" void kernel_launch(void* const* d_in, const int* in_sizes, int n_in,
                              void* d_out, int out_size, void* d_ws, size_t ws_size,
                              hipStream_t stream) {
    const float* x     = (const float*)d_in[0];
    const float* Wfc   = (const float*)d_in[1];
    const float* a_l   = (const float*)d_in[2];
    const float* a_r   = (const float*)d_in[3];
    const float* gamma = (const float*)d_in[4];
    const float* beta  = (const float*)d_in[5];
    const float* W1    = (const float*)d_in[6];
    const float* b1    = (const float*)d_in[7];
    const float* W2    = (const float*)d_in[8];
    const float* b2    = (const float*)d_in[9];
    const int*   es    = (const int*)d_in[10];
    const int*   ed    = (const int*)d_in[11];
    float* out = (float*)d_out;

    bf16_t* W1T = (bf16_t*)d_ws;              // 512*128
    bf16_t* W2T = W1T + 512 * 128;            // 128*512
    float* z  = (float*)(W2T + 128 * 512);    // N*128
    float* el = z + (size_t)N_NODES * 128;    // N*8
    float* er = el + N_NODES * 8;             // N*8
    int* counts  = (int*)(er + N_NODES * 8);  // N
    int* csr_off = counts + N_NODES;          // N+1
    int* cursor  = csr_off + N_NODES + 1;     // N+1
    int* csr_src = cursor + N_NODES + 1;      // E
    int* bsum    = csr_src + E_EDGES;         // SCAN_BLOCKS
    int* boff    = bsum + 128;                // 128

    k_zero<<<dim3((N_NODES + 255) / 256), dim3(256), 0, stream>>>(counts);
    k_count<<<dim3((E_EDGES + 255) / 256), dim3(256), 0, stream>>>(ed, counts);
    k_scan1<<<dim3(SCAN_BLOCKS), dim3(512), 0, stream>>>(counts, bsum);
    k_scan2<<<dim3(1), dim3(128), 0, stream>>>(bsum, boff);
    k_scan3<<<dim3(SCAN_BLOCKS), dim3(512), 0, stream>>>(counts, boff, csr_off, cursor);
    k_fill<<<dim3((E_EDGES + 255) / 256), dim3(256), 0, stream>>>(es, ed, cursor, csr_src);
    k_prep<<<dim3(256), dim3(256), 0, stream>>>(W1, W2, W1T, W2T);
    k_proj<<<dim3((N_NODES + 63) / 64), dim3(512), 0, stream>>>(x, Wfc, z);
    k_el_er<<<dim3((N_NODES * H_HEADS + 255) / 256), dim3(256), 0, stream>>>(z, a_l, a_r, el, er);
    k_node<<<dim3((N_NODES + 3) / 4), dim3(256), 0, stream>>>(csr_off, csr_src, el, er, z, out);
    k_ffn<<<dim3((N_NODES + 63) / 64), dim3(512), 0, stream>>>(x, gamma, beta, W1T, b1, W2T, b2, out);
}

// Round 5
// 293.527 us; speedup vs baseline: 5.5586x; 1.0249x over previous
//
#include <hip/hip_runtime.h>
#include <math.h>

#define N_NODES 50000
#define E_EDGES 800000
#define D_DIM   128
#define H_HEADS 8
#define DH_DIM  16
#define DFF     512

#define SCAN_BLOCKS 98  // 98*512 = 50176 >= N_NODES+1

typedef __bf16 bf16_t;
typedef bf16_t bf16x8 __attribute__((ext_vector_type(8)));
typedef float f32x4 __attribute__((ext_vector_type(4)));
typedef unsigned short u16x8 __attribute__((ext_vector_type(8)));

#define SWZ(r) (((r) & 7) << 4)

__device__ __forceinline__ float lrelu(float v) { return v > 0.f ? v : 0.01f * v; }
__device__ __forceinline__ unsigned short f2b(float f) {
    unsigned u = __float_as_uint(f);
    unsigned r = (u + 0x7FFFu + ((u >> 16) & 1u)) >> 16;
    return (unsigned short)r;
}

// ---------------- zero counts ----------------
__global__ void k_zero(int* __restrict__ counts) {
    int i = blockIdx.x * 256 + threadIdx.x;
    if (i < N_NODES) counts[i] = 0;
}

// ---------------- count in-degree ----------------
__global__ void k_count(const int* __restrict__ ed, int* __restrict__ counts) {
    int e = blockIdx.x * 256 + threadIdx.x;
    if (e < E_EDGES) atomicAdd(&counts[ed[e]], 1);
}

// ---------------- hierarchical scan ----------------
__global__ __launch_bounds__(512) void k_scan1(const int* __restrict__ counts,
                                               int* __restrict__ bsum) {
    int i = blockIdx.x * 512 + threadIdx.x;
    int v = (i < N_NODES) ? counts[i] : 0;
    #pragma unroll
    for (int o = 1; o < 64; o <<= 1) v += __shfl_xor(v, o);
    __shared__ int ws[8];
    if ((threadIdx.x & 63) == 0) ws[threadIdx.x >> 6] = v;
    __syncthreads();
    if (threadIdx.x == 0) {
        int s = 0;
        #pragma unroll
        for (int k = 0; k < 8; ++k) s += ws[k];
        bsum[blockIdx.x] = s;
    }
}

__global__ __launch_bounds__(128) void k_scan2(const int* __restrict__ bsum,
                                               int* __restrict__ boff) {
    __shared__ int tmp[128];
    int t = threadIdx.x;
    int v = (t < SCAN_BLOCKS) ? bsum[t] : 0;
    tmp[t] = v;
    __syncthreads();
    for (int o = 1; o < 128; o <<= 1) {
        int u = (t >= o) ? tmp[t - o] : 0;
        __syncthreads();
        tmp[t] += u;
        __syncthreads();
    }
    boff[t] = (t == 0) ? 0 : tmp[t - 1];
}

__global__ __launch_bounds__(512) void k_scan3(const int* __restrict__ counts,
                                               const int* __restrict__ boff,
                                               int* __restrict__ csr_off,
                                               int* __restrict__ cursor) {
    int t = threadIdx.x;
    int i = blockIdx.x * 512 + t;
    int v = (i < N_NODES) ? counts[i] : 0;
    int lane = t & 63, w = t >> 6;
    int xs = v;
    #pragma unroll
    for (int o = 1; o < 64; o <<= 1) {
        int u = __shfl_up(xs, o);
        if (lane >= o) xs += u;
    }
    __shared__ int ws[8];
    __shared__ int wo[8];
    if (lane == 63) ws[w] = xs;
    __syncthreads();
    if (t == 0) {
        int s = 0;
        #pragma unroll
        for (int k = 0; k < 8; ++k) { wo[k] = s; s += ws[k]; }
    }
    __syncthreads();
    int excl = xs - v + wo[w] + boff[blockIdx.x];
    if (i < N_NODES) { csr_off[i] = excl; cursor[i] = excl; }
    if (i == N_NODES) csr_off[N_NODES] = E_EDGES;
}

// ---------------- fill CSR with src ids ----------------
__global__ void k_fill(const int* __restrict__ es, const int* __restrict__ ed,
                       int* __restrict__ cursor, int* __restrict__ csr_src) {
    int e = blockIdx.x * 256 + threadIdx.x;
    if (e < E_EDGES) {
        int pos = atomicAdd(&cursor[ed[e]], 1);
        csr_src[pos] = es[e];
    }
}

// ---------------- weight prep: transpose + bf16 ----------------
__global__ void k_prep(const float* __restrict__ W1, const float* __restrict__ W2,
                       bf16_t* __restrict__ W1T, bf16_t* __restrict__ W2T) {
    int id = blockIdx.x * 256 + threadIdx.x;
    if (id < 512 * 128) {
        int c = id >> 7, k = id & 127;
        W1T[id] = (bf16_t)W1[(size_t)k * 512 + c];
        int c2 = id >> 9, k2 = id & 511;
        W2T[id] = (bf16_t)W2[(size_t)k2 * 128 + c2];
    }
}

// ---------------- z = x @ Wp -> zb (bf16) + fused el/er ----------------
__global__ __launch_bounds__(512) void k_proj(const float* __restrict__ x,
                                              const float* __restrict__ Wfc,
                                              const float* __restrict__ a_l,
                                              const float* __restrict__ a_r,
                                              unsigned short* __restrict__ zb,
                                              float* __restrict__ el,
                                              float* __restrict__ er) {
    __shared__ float xT[128 * 68];
    __shared__ float Wp[128 * 132];
    int t = threadIdx.x;
    int r0 = blockIdx.x * 64;
    for (int lin = t; lin < 64 * 128; lin += 512) {
        int r = lin >> 7, d = lin & 127;
        float v = 0.f;
        if (r0 + r < N_NODES) v = x[(r0 + r) * 128 + d];
        xT[d * 68 + r] = v;
    }
    for (int lin = t; lin < 4096; lin += 512) {
        int d = lin >> 5;
        int rem = lin & 31;
        int h = rem >> 2, q = (rem & 3) * 4;
        float4 w = *(const float4*)(Wfc + h * 2048 + d * 16 + q);
        *(float4*)&Wp[d * 132 + h * 16 + q] = w;
    }
    __syncthreads();
    int ct = t & 31, rt = t >> 5;
    int c0 = ct * 4, rr = rt * 4;
    float acc[4][4] = {};
    #pragma unroll 4
    for (int d = 0; d < 128; ++d) {
        float4 xv = *(const float4*)&xT[d * 68 + rr];
        float4 wv = *(const float4*)&Wp[d * 132 + c0];
        float xa[4] = {xv.x, xv.y, xv.z, xv.w};
        float wa[4] = {wv.x, wv.y, wv.z, wv.w};
        #pragma unroll
        for (int i = 0; i < 4; ++i)
            #pragma unroll
            for (int j = 0; j < 4; ++j) acc[i][j] += xa[i] * wa[j];
    }
    // zb write (bf16)
    #pragma unroll
    for (int i = 0; i < 4; ++i) {
        int r = r0 + rr + i;
        if (r < N_NODES) {
            ushort4 pk;
            pk.x = f2b(acc[i][0]); pk.y = f2b(acc[i][1]);
            pk.z = f2b(acc[i][2]); pk.w = f2b(acc[i][3]);
            *(ushort4*)&zb[(size_t)r * 128 + c0] = pk;
        }
    }
    // fused el/er: this thread's 4 cols are within head h = ct>>2
    int h = ct >> 2;
    float4 alv = *(const float4*)&a_l[h * 16 + (c0 & 15)];
    float4 arv = *(const float4*)&a_r[h * 16 + (c0 & 15)];
    float pl[4], pr[4];
    #pragma unroll
    for (int i = 0; i < 4; ++i) {
        pl[i] = acc[i][0] * alv.x + acc[i][1] * alv.y + acc[i][2] * alv.z + acc[i][3] * alv.w;
        pr[i] = acc[i][0] * arv.x + acc[i][1] * arv.y + acc[i][2] * arv.z + acc[i][3] * arv.w;
    }
    #pragma unroll
    for (int i = 0; i < 4; ++i) {
        pl[i] += __shfl_xor(pl[i], 1); pl[i] += __shfl_xor(pl[i], 2);
        pr[i] += __shfl_xor(pr[i], 1); pr[i] += __shfl_xor(pr[i], 2);
    }
    int ii = ct & 3;
    int row = r0 + rr + ii;
    if (row < N_NODES) {
        el[row * 8 + h] = pl[ii];
        er[row * 8 + h] = pr[ii];
    }
}

// ---------------- fused per-node softmax + aggregate (wave per node) --------
__global__ __launch_bounds__(256) void k_node(const int* __restrict__ csr_off,
                                              const int* __restrict__ csr_src,
                                              const float* __restrict__ el,
                                              const float* __restrict__ er,
                                              const unsigned short* __restrict__ zb,
                                              float* __restrict__ out) {
    int n = blockIdx.x * 4 + (threadIdx.x >> 6);
    if (n >= N_NODES) return;
    int lane = threadIdx.x & 63;
    int h = lane >> 3, s = lane & 7;
    int row = csr_off[n];
    int deg = csr_off[n + 1] - row;
    if (deg == 0) {
        *(float2*)&out[(size_t)n * 128 + lane * 2] = make_float2(0.f, 0.f);
        return;
    }
    float erv = er[n * 8 + h];
    int nch = (deg + 7) >> 3;

    float ev[8];
    int srcv[8];
    float mx = -INFINITY;
    for (int c = 0; c < nch; ++c) {
        int k = c * 8 + s;
        int src = 0;
        float e = -INFINITY;
        if (k < deg) {
            src = csr_src[row + k];
            e = lrelu(el[src * 8 + h] + erv);
        }
        if (c < 8) { ev[c] = e; srcv[c] = src; }
        mx = fmaxf(mx, e);
    }
    mx = fmaxf(mx, __shfl_xor(mx, 1));
    mx = fmaxf(mx, __shfl_xor(mx, 2));
    mx = fmaxf(mx, __shfl_xor(mx, 4));

    float ps = 0.f;
    float2 acc = make_float2(0.f, 0.f);
    int hj = lane >> 3;
    for (int c = 0; c < nch; ++c) {
        int k = c * 8 + s;
        float e;
        int src;
        if (c < 8) {
            e = ev[c]; src = srcv[c];
        } else {
            src = 0; e = -INFINITY;
            if (k < deg) {
                src = csr_src[row + k];
                e = lrelu(el[src * 8 + h] + erv);
            }
        }
        float p = (k < deg) ? __expf(e - mx) : 0.f;
        ps += p;
        int lim = min(8, deg - c * 8);
        for (int tt = 0; tt < lim; ++tt) {
            float a = __shfl(p, hj * 8 + tt);
            int se = __shfl(src, tt);
            unsigned u = *(const unsigned*)&zb[(size_t)se * 128 + lane * 2];
            acc.x += a * __uint_as_float(u << 16);
            acc.y += a * __uint_as_float(u & 0xFFFF0000u);
        }
    }
    ps += __shfl_xor(ps, 1);
    ps += __shfl_xor(ps, 2);
    ps += __shfl_xor(ps, 4);
    float sumh = __shfl(ps, hj * 8);
    float inv = 1.f / fmaxf(sumh, 1e-9f);
    *(float2*)&out[(size_t)n * 128 + lane * 2] = make_float2(acc.x * inv, acc.y * inv);
}

// ---------------- fused elu+residual+LN+FFN with bf16 MFMA ----------------
__global__ __launch_bounds__(512, 4) void k_ffn(const float* __restrict__ x,
                                                const float* __restrict__ gamma,
                                                const float* __restrict__ beta,
                                                const bf16_t* __restrict__ W1T,
                                                const float* __restrict__ b1,
                                                const bf16_t* __restrict__ W2T,
                                                const float* __restrict__ b2,
                                                float* __restrict__ out) {
    __shared__ char smem[81920];
    char* lnA = smem;           // bf16[64][128], row stride 256B, XOR-swizzled
    char* inA = smem + 16384;   // bf16[64][512], row stride 1024B, XOR-swizzled
    int t = threadIdx.x;
    int r0 = blockIdx.x * 64;

    {
        int r = t >> 3, c0 = (t & 7) * 16;
        int gr = r0 + r;
        float hv[16];
        if (gr < N_NODES) {
            #pragma unroll
            for (int q = 0; q < 4; ++q) {
                float4 g4 = *(const float4*)&out[(size_t)gr * 128 + c0 + q * 4];
                float4 x4 = *(const float4*)&x[(size_t)gr * 128 + c0 + q * 4];
                float ga[4] = {g4.x, g4.y, g4.z, g4.w};
                float xa[4] = {x4.x, x4.y, x4.z, x4.w};
                #pragma unroll
                for (int i = 0; i < 4; ++i) {
                    float g = ga[i] > 0.f ? ga[i] : expm1f(ga[i]);
                    hv[q * 4 + i] = xa[i] + g;
                }
            }
        } else {
            #pragma unroll
            for (int i = 0; i < 16; ++i) hv[i] = 0.f;
        }
        float sm = 0.f, sq = 0.f;
        #pragma unroll
        for (int i = 0; i < 16; ++i) { sm += hv[i]; sq += hv[i] * hv[i]; }
        sm += __shfl_xor(sm, 1); sq += __shfl_xor(sq, 1);
        sm += __shfl_xor(sm, 2); sq += __shfl_xor(sq, 2);
        sm += __shfl_xor(sm, 4); sq += __shfl_xor(sq, 4);
        float mu = sm * (1.f / 128.f);
        float rs = rsqrtf(sq * (1.f / 128.f) - mu * mu + 1e-5f);
        u16x8 pk0, pk1;
        #pragma unroll
        for (int i = 0; i < 8; ++i) {
            pk0[i] = f2b((hv[i] - mu) * rs * gamma[c0 + i] + beta[c0 + i]);
            pk1[i] = f2b((hv[8 + i] - mu) * rs * gamma[c0 + 8 + i] + beta[c0 + 8 + i]);
        }
        int base = r * 256 + c0 * 2;
        *(u16x8*)(lnA + (base ^ SWZ(r))) = pk0;
        *(u16x8*)(lnA + ((base + 16) ^ SWZ(r))) = pk1;
    }
    __syncthreads();

    int wv = t >> 6, l = t & 63;
    int lr = l & 15, lg = l >> 4;

    {
        int n0 = wv * 64;
        f32x4 acc[4][4] = {};
        #pragma unroll
        for (int ks = 0; ks < 4; ++ks) {
            bf16x8 a[4], b[4];
            #pragma unroll
            for (int mi = 0; mi < 4; ++mi) {
                int row = mi * 16 + lr;
                int off = (row * 256 + ks * 64 + lg * 16) ^ SWZ(row);
                a[mi] = *(const bf16x8*)(lnA + off);
            }
            #pragma unroll
            for (int ni = 0; ni < 4; ++ni) {
                int c = n0 + ni * 16 + lr;
                b[ni] = *(const bf16x8*)(W1T + (size_t)c * 128 + ks * 32 + lg * 8);
            }
            #pragma unroll
            for (int mi = 0; mi < 4; ++mi)
                #pragma unroll
                for (int ni = 0; ni < 4; ++ni)
                    acc[mi][ni] = __builtin_amdgcn_mfma_f32_16x16x32_bf16(
                        a[mi], b[ni], acc[mi][ni], 0, 0, 0);
        }
        #pragma unroll
        for (int ni = 0; ni < 4; ++ni) {
            int c = n0 + ni * 16 + lr;
            float bb = b1[c];
            #pragma unroll
            for (int mi = 0; mi < 4; ++mi) {
                #pragma unroll
                for (int rg = 0; rg < 4; ++rg) {
                    int row = mi * 16 + lg * 4 + rg;
                    float v = acc[mi][ni][rg] + bb;
                    v = v > 0.f ? v : 0.f;
                    *(unsigned short*)(inA + ((row * 1024 + c * 2) ^ SWZ(row))) = f2b(v);
                }
            }
        }
    }
    __syncthreads();

    {
        int n2 = wv * 16;
        f32x4 acc2[4] = {};
        #pragma unroll
        for (int ks = 0; ks < 16; ++ks) {
            bf16x8 bfr = *(const bf16x8*)(W2T + (size_t)(n2 + lr) * 512 + ks * 32 + lg * 8);
            #pragma unroll
            for (int mi = 0; mi < 4; ++mi) {
                int row = mi * 16 + lr;
                int off = (row * 1024 + ks * 64 + lg * 16) ^ SWZ(row);
                bf16x8 a2 = *(const bf16x8*)(inA + off);
                acc2[mi] = __builtin_amdgcn_mfma_f32_16x16x32_bf16(a2, bfr, acc2[mi], 0, 0, 0);
            }
        }
        float bb2 = b2[n2 + lr];
        #pragma unroll
        for (int mi = 0; mi < 4; ++mi) {
            #pragma unroll
            for (int rg = 0; rg < 4; ++rg) {
                int row = mi * 16 + lg * 4 + rg;
                int gr = r0 + row;
                if (gr < N_NODES) {
                    size_t idx = (size_t)gr * 128 + n2 + lr;
                    float g = out[idx];
                    g = g > 0.f ? g : expm1f(g);
                    out[idx] = acc2[mi][rg] + bb2 + x[idx] + g;
                }
            }
        }
    }
}

extern "C" void kernel_launch(void* const* d_in, const int* in_sizes, int n_in,
                              void* d_out, int out_size, void* d_ws, size_t ws_size,
                              hipStream_t stream) {
    const float* x     = (const float*)d_in[0];
    const float* Wfc   = (const float*)d_in[1];
    const float* a_l   = (const float*)d_in[2];
    const float* a_r   = (const float*)d_in[3];
    const float* gamma = (const float*)d_in[4];
    const float* beta  = (const float*)d_in[5];
    const float* W1    = (const float*)d_in[6];
    const float* b1    = (const float*)d_in[7];
    const float* W2    = (const float*)d_in[8];
    const float* b2    = (const float*)d_in[9];
    const int*   es    = (const int*)d_in[10];
    const int*   ed    = (const int*)d_in[11];
    float* out = (float*)d_out;

    bf16_t* W1T = (bf16_t*)d_ws;                      // 512*128
    bf16_t* W2T = W1T + 512 * 128;                    // 128*512
    unsigned short* zb = (unsigned short*)(W2T + 128 * 512);  // N*128 bf16
    float* el = (float*)(zb + (size_t)N_NODES * 128); // N*8
    float* er = el + N_NODES * 8;                     // N*8
    int* counts  = (int*)(er + N_NODES * 8);          // N
    int* csr_off = counts + N_NODES;                  // N+1
    int* cursor  = csr_off + N_NODES + 1;             // N+1
    int* csr_src = cursor + N_NODES + 1;              // E
    int* bsum    = csr_src + E_EDGES;                 // SCAN_BLOCKS
    int* boff    = bsum + 128;                        // 128

    k_zero<<<dim3((N_NODES + 255) / 256), dim3(256), 0, stream>>>(counts);
    k_count<<<dim3((E_EDGES + 255) / 256), dim3(256), 0, stream>>>(ed, counts);
    k_scan1<<<dim3(SCAN_BLOCKS), dim3(512), 0, stream>>>(counts, bsum);
    k_scan2<<<dim3(1), dim3(128), 0, stream>>>(bsum, boff);
    k_scan3<<<dim3(SCAN_BLOCKS), dim3(512), 0, stream>>>(counts, boff, csr_off, cursor);
    k_fill<<<dim3((E_EDGES + 255) / 256), dim3(256), 0, stream>>>(es, ed, cursor, csr_src);
    k_prep<<<dim3(256), dim3(256), 0, stream>>>(W1, W2, W1T, W2T);
    k_proj<<<dim3((N_NODES + 63) / 64), dim3(512), 0, stream>>>(x, Wfc, a_l, a_r, zb, el, er);
    k_node<<<dim3((N_NODES + 3) / 4), dim3(256), 0, stream>>>(csr_off, csr_src, el, er, zb, out);
    k_ffn<<<dim3((N_NODES + 63) / 64), dim3(512), 0, stream>>>(x, gamma, beta, W1T, b1, W2T, b2, out);
}

// Round 6
// 269.552 us; speedup vs baseline: 6.0530x; 1.0889x over previous
//
#include <hip/hip_runtime.h>
#include <math.h>

#define N_NODES 50000
#define E_EDGES 800000
#define D_DIM   128
#define H_HEADS 8
#define DH_DIM  16
#define DFF     512

#define SCAN_BLOCKS 98  // 98*512 = 50176 >= N_NODES+1

typedef __bf16 bf16_t;
typedef bf16_t bf16x8 __attribute__((ext_vector_type(8)));
typedef float f32x4 __attribute__((ext_vector_type(4)));
typedef unsigned short u16x8 __attribute__((ext_vector_type(8)));

#define SWZ(r) (((r) & 7) << 4)

__device__ __forceinline__ float lrelu(float v) { return v > 0.f ? v : 0.01f * v; }
__device__ __forceinline__ unsigned short f2b(float f) {
    unsigned u = __float_as_uint(f);
    unsigned r = (u + 0x7FFFu + ((u >> 16) & 1u)) >> 16;
    return (unsigned short)r;
}

// ---------------- zero counts ----------------
__global__ void k_zero(int* __restrict__ counts) {
    int i = blockIdx.x * 256 + threadIdx.x;
    if (i < N_NODES) counts[i] = 0;
}

// ---------------- count in-degree ----------------
__global__ void k_count(const int* __restrict__ ed, int* __restrict__ counts) {
    int e = blockIdx.x * 256 + threadIdx.x;
    if (e < E_EDGES) atomicAdd(&counts[ed[e]], 1);
}

// ---------------- hierarchical scan ----------------
__global__ __launch_bounds__(512) void k_scan1(const int* __restrict__ counts,
                                               int* __restrict__ bsum) {
    int i = blockIdx.x * 512 + threadIdx.x;
    int v = (i < N_NODES) ? counts[i] : 0;
    #pragma unroll
    for (int o = 1; o < 64; o <<= 1) v += __shfl_xor(v, o);
    __shared__ int ws[8];
    if ((threadIdx.x & 63) == 0) ws[threadIdx.x >> 6] = v;
    __syncthreads();
    if (threadIdx.x == 0) {
        int s = 0;
        #pragma unroll
        for (int k = 0; k < 8; ++k) s += ws[k];
        bsum[blockIdx.x] = s;
    }
}

__global__ __launch_bounds__(128) void k_scan2(const int* __restrict__ bsum,
                                               int* __restrict__ boff) {
    __shared__ int tmp[128];
    int t = threadIdx.x;
    int v = (t < SCAN_BLOCKS) ? bsum[t] : 0;
    tmp[t] = v;
    __syncthreads();
    for (int o = 1; o < 128; o <<= 1) {
        int u = (t >= o) ? tmp[t - o] : 0;
        __syncthreads();
        tmp[t] += u;
        __syncthreads();
    }
    boff[t] = (t == 0) ? 0 : tmp[t - 1];
}

__global__ __launch_bounds__(512) void k_scan3(const int* __restrict__ counts,
                                               const int* __restrict__ boff,
                                               int* __restrict__ csr_off,
                                               int* __restrict__ cursor) {
    int t = threadIdx.x;
    int i = blockIdx.x * 512 + t;
    int v = (i < N_NODES) ? counts[i] : 0;
    int lane = t & 63, w = t >> 6;
    int xs = v;
    #pragma unroll
    for (int o = 1; o < 64; o <<= 1) {
        int u = __shfl_up(xs, o);
        if (lane >= o) xs += u;
    }
    __shared__ int ws[8];
    __shared__ int wo[8];
    if (lane == 63) ws[w] = xs;
    __syncthreads();
    if (t == 0) {
        int s = 0;
        #pragma unroll
        for (int k = 0; k < 8; ++k) { wo[k] = s; s += ws[k]; }
    }
    __syncthreads();
    int excl = xs - v + wo[w] + boff[blockIdx.x];
    if (i < N_NODES) { csr_off[i] = excl; cursor[i] = excl; }
    if (i == N_NODES) csr_off[N_NODES] = E_EDGES;
}

// ---------------- fill CSR with src ids ----------------
__global__ void k_fill(const int* __restrict__ es, const int* __restrict__ ed,
                       int* __restrict__ cursor, int* __restrict__ csr_src) {
    int e = blockIdx.x * 256 + threadIdx.x;
    if (e < E_EDGES) {
        int pos = atomicAdd(&cursor[ed[e]], 1);
        csr_src[pos] = es[e];
    }
}

// ---------------- weight prep: transpose + bf16 ----------------
__global__ void k_prep(const float* __restrict__ W1, const float* __restrict__ W2,
                       bf16_t* __restrict__ W1T, bf16_t* __restrict__ W2T) {
    int id = blockIdx.x * 256 + threadIdx.x;
    if (id < 512 * 128) {
        int c = id >> 7, k = id & 127;
        W1T[id] = (bf16_t)W1[(size_t)k * 512 + c];
        int c2 = id >> 9, k2 = id & 511;
        W2T[id] = (bf16_t)W2[(size_t)k2 * 128 + c2];
    }
}

// ---------------- z = x @ Wp -> zb (bf16) + fused el/er ----------------
__global__ __launch_bounds__(512) void k_proj(const float* __restrict__ x,
                                              const float* __restrict__ Wfc,
                                              const float* __restrict__ a_l,
                                              const float* __restrict__ a_r,
                                              unsigned short* __restrict__ zb,
                                              float* __restrict__ el,
                                              float* __restrict__ er) {
    __shared__ float xT[128 * 68];
    __shared__ float Wp[128 * 132];
    int t = threadIdx.x;
    int r0 = blockIdx.x * 64;
    for (int lin = t; lin < 64 * 128; lin += 512) {
        int r = lin >> 7, d = lin & 127;
        float v = 0.f;
        if (r0 + r < N_NODES) v = x[(r0 + r) * 128 + d];
        xT[d * 68 + r] = v;
    }
    for (int lin = t; lin < 4096; lin += 512) {
        int d = lin >> 5;
        int rem = lin & 31;
        int h = rem >> 2, q = (rem & 3) * 4;
        float4 w = *(const float4*)(Wfc + h * 2048 + d * 16 + q);
        *(float4*)&Wp[d * 132 + h * 16 + q] = w;
    }
    __syncthreads();
    int ct = t & 31, rt = t >> 5;
    int c0 = ct * 4, rr = rt * 4;
    float acc[4][4] = {};
    #pragma unroll 4
    for (int d = 0; d < 128; ++d) {
        float4 xv = *(const float4*)&xT[d * 68 + rr];
        float4 wv = *(const float4*)&Wp[d * 132 + c0];
        float xa[4] = {xv.x, xv.y, xv.z, xv.w};
        float wa[4] = {wv.x, wv.y, wv.z, wv.w};
        #pragma unroll
        for (int i = 0; i < 4; ++i)
            #pragma unroll
            for (int j = 0; j < 4; ++j) acc[i][j] += xa[i] * wa[j];
    }
    // zb write (bf16)
    #pragma unroll
    for (int i = 0; i < 4; ++i) {
        int r = r0 + rr + i;
        if (r < N_NODES) {
            ushort4 pk;
            pk.x = f2b(acc[i][0]); pk.y = f2b(acc[i][1]);
            pk.z = f2b(acc[i][2]); pk.w = f2b(acc[i][3]);
            *(ushort4*)&zb[(size_t)r * 128 + c0] = pk;
        }
    }
    // fused el/er: this thread's 4 cols are within head h = ct>>2
    int h = ct >> 2;
    float4 alv = *(const float4*)&a_l[h * 16 + (c0 & 15)];
    float4 arv = *(const float4*)&a_r[h * 16 + (c0 & 15)];
    float pl[4], pr[4];
    #pragma unroll
    for (int i = 0; i < 4; ++i) {
        pl[i] = acc[i][0] * alv.x + acc[i][1] * alv.y + acc[i][2] * alv.z + acc[i][3] * alv.w;
        pr[i] = acc[i][0] * arv.x + acc[i][1] * arv.y + acc[i][2] * arv.z + acc[i][3] * arv.w;
    }
    #pragma unroll
    for (int i = 0; i < 4; ++i) {
        pl[i] += __shfl_xor(pl[i], 1); pl[i] += __shfl_xor(pl[i], 2);
        pr[i] += __shfl_xor(pr[i], 1); pr[i] += __shfl_xor(pr[i], 2);
    }
    int ii = ct & 3;
    int row = r0 + rr + ii;
    if (row < N_NODES) {
        el[row * 8 + h] = pl[ii];
        er[row * 8 + h] = pr[ii];
    }
}

// ---------------- fused per-node softmax + aggregate (wave per node) --------
// lane = h*8 + s. Pass 2 fully unrolled per 8-edge chunk for MLP:
// OOB edges carry p=0 (from source lane) and src=0 (safe address).
__global__ __launch_bounds__(256) void k_node(const int* __restrict__ csr_off,
                                              const int* __restrict__ csr_src,
                                              const float* __restrict__ el,
                                              const float* __restrict__ er,
                                              const unsigned short* __restrict__ zb,
                                              float* __restrict__ out) {
    int n = blockIdx.x * 4 + (threadIdx.x >> 6);
    if (n >= N_NODES) return;
    int lane = threadIdx.x & 63;
    int h = lane >> 3, s = lane & 7;
    int row = csr_off[n];
    int deg = csr_off[n + 1] - row;
    if (deg == 0) {
        *(float2*)&out[(size_t)n * 128 + lane * 2] = make_float2(0.f, 0.f);
        return;
    }
    float erv = er[n * 8 + h];
    int nch = (deg + 7) >> 3;

    float ev[8];
    int srcv[8];
    float mx = -INFINITY;
    for (int c = 0; c < nch; ++c) {
        int k = c * 8 + s;
        int src = 0;
        float e = -INFINITY;
        if (k < deg) {
            src = csr_src[row + k];
            e = lrelu(el[src * 8 + h] + erv);
        }
        if (c < 8) { ev[c] = e; srcv[c] = src; }
        mx = fmaxf(mx, e);
    }
    mx = fmaxf(mx, __shfl_xor(mx, 1));
    mx = fmaxf(mx, __shfl_xor(mx, 2));
    mx = fmaxf(mx, __shfl_xor(mx, 4));

    float ps = 0.f;
    float2 acc = make_float2(0.f, 0.f);
    int hj = lane >> 3;
    const unsigned short* zbl = zb + lane * 2;
    for (int c = 0; c < nch; ++c) {
        // own (h, s) values for this chunk
        float e;
        int src;
        if (c < 8) {
            e = ev[c]; src = srcv[c];
        } else {
            int k = c * 8 + s;
            src = 0; e = -INFINITY;
            if (k < deg) {
                src = csr_src[row + k];
                e = lrelu(el[src * 8 + h] + erv);
            }
        }
        float p = ((c * 8 + s) < deg) ? __expf(e - mx) : 0.f;
        ps += p;
        // transpose within head group: alpha + src for all 8 edges of chunk
        float a[8];
        int se[8];
        #pragma unroll
        for (int tt = 0; tt < 8; ++tt) {
            a[tt] = __shfl(p, hj * 8 + tt);
            se[tt] = __shfl(src, tt);
        }
        // 8 independent gathers
        unsigned u[8];
        #pragma unroll
        for (int tt = 0; tt < 8; ++tt)
            u[tt] = *(const unsigned*)(zbl + (size_t)se[tt] * 128);
        #pragma unroll
        for (int tt = 0; tt < 8; ++tt) {
            acc.x += a[tt] * __uint_as_float(u[tt] << 16);
            acc.y += a[tt] * __uint_as_float(u[tt] & 0xFFFF0000u);
        }
    }
    ps += __shfl_xor(ps, 1);
    ps += __shfl_xor(ps, 2);
    ps += __shfl_xor(ps, 4);
    float sumh = __shfl(ps, hj * 8);
    float inv = 1.f / fmaxf(sumh, 1e-9f);
    *(float2*)&out[(size_t)n * 128 + lane * 2] = make_float2(acc.x * inv, acc.y * inv);
}

// ---------------- fused elu+residual+LN+FFN with bf16 MFMA ----------------
__global__ __launch_bounds__(512, 4) void k_ffn(const float* __restrict__ x,
                                                const float* __restrict__ gamma,
                                                const float* __restrict__ beta,
                                                const bf16_t* __restrict__ W1T,
                                                const float* __restrict__ b1,
                                                const bf16_t* __restrict__ W2T,
                                                const float* __restrict__ b2,
                                                float* __restrict__ out) {
    __shared__ char smem[81920];
    char* lnA = smem;           // bf16[64][128], row stride 256B, XOR-swizzled
    char* inA = smem + 16384;   // bf16[64][512], row stride 1024B, XOR-swizzled
    int t = threadIdx.x;
    int r0 = blockIdx.x * 64;

    {
        int r = t >> 3, c0 = (t & 7) * 16;
        int gr = r0 + r;
        float hv[16];
        if (gr < N_NODES) {
            #pragma unroll
            for (int q = 0; q < 4; ++q) {
                float4 g4 = *(const float4*)&out[(size_t)gr * 128 + c0 + q * 4];
                float4 x4 = *(const float4*)&x[(size_t)gr * 128 + c0 + q * 4];
                float ga[4] = {g4.x, g4.y, g4.z, g4.w};
                float xa[4] = {x4.x, x4.y, x4.z, x4.w};
                #pragma unroll
                for (int i = 0; i < 4; ++i) {
                    float g = ga[i] > 0.f ? ga[i] : expm1f(ga[i]);
                    hv[q * 4 + i] = xa[i] + g;
                }
            }
        } else {
            #pragma unroll
            for (int i = 0; i < 16; ++i) hv[i] = 0.f;
        }
        float sm = 0.f, sq = 0.f;
        #pragma unroll
        for (int i = 0; i < 16; ++i) { sm += hv[i]; sq += hv[i] * hv[i]; }
        sm += __shfl_xor(sm, 1); sq += __shfl_xor(sq, 1);
        sm += __shfl_xor(sm, 2); sq += __shfl_xor(sq, 2);
        sm += __shfl_xor(sm, 4); sq += __shfl_xor(sq, 4);
        float mu = sm * (1.f / 128.f);
        float rs = rsqrtf(sq * (1.f / 128.f) - mu * mu + 1e-5f);
        u16x8 pk0, pk1;
        #pragma unroll
        for (int i = 0; i < 8; ++i) {
            pk0[i] = f2b((hv[i] - mu) * rs * gamma[c0 + i] + beta[c0 + i]);
            pk1[i] = f2b((hv[8 + i] - mu) * rs * gamma[c0 + 8 + i] + beta[c0 + 8 + i]);
        }
        int base = r * 256 + c0 * 2;
        *(u16x8*)(lnA + (base ^ SWZ(r))) = pk0;
        *(u16x8*)(lnA + ((base + 16) ^ SWZ(r))) = pk1;
    }
    __syncthreads();

    int wv = t >> 6, l = t & 63;
    int lr = l & 15, lg = l >> 4;

    {
        int n0 = wv * 64;
        f32x4 acc[4][4] = {};
        #pragma unroll
        for (int ks = 0; ks < 4; ++ks) {
            bf16x8 a[4], b[4];
            #pragma unroll
            for (int mi = 0; mi < 4; ++mi) {
                int row = mi * 16 + lr;
                int off = (row * 256 + ks * 64 + lg * 16) ^ SWZ(row);
                a[mi] = *(const bf16x8*)(lnA + off);
            }
            #pragma unroll
            for (int ni = 0; ni < 4; ++ni) {
                int c = n0 + ni * 16 + lr;
                b[ni] = *(const bf16x8*)(W1T + (size_t)c * 128 + ks * 32 + lg * 8);
            }
            #pragma unroll
            for (int mi = 0; mi < 4; ++mi)
                #pragma unroll
                for (int ni = 0; ni < 4; ++ni)
                    acc[mi][ni] = __builtin_amdgcn_mfma_f32_16x16x32_bf16(
                        a[mi], b[ni], acc[mi][ni], 0, 0, 0);
        }
        #pragma unroll
        for (int ni = 0; ni < 4; ++ni) {
            int c = n0 + ni * 16 + lr;
            float bb = b1[c];
            #pragma unroll
            for (int mi = 0; mi < 4; ++mi) {
                #pragma unroll
                for (int rg = 0; rg < 4; ++rg) {
                    int row = mi * 16 + lg * 4 + rg;
                    float v = acc[mi][ni][rg] + bb;
                    v = v > 0.f ? v : 0.f;
                    *(unsigned short*)(inA + ((row * 1024 + c * 2) ^ SWZ(row))) = f2b(v);
                }
            }
        }
    }
    __syncthreads();

    {
        int n2 = wv * 16;
        f32x4 acc2[4] = {};
        #pragma unroll
        for (int ks = 0; ks < 16; ++ks) {
            bf16x8 bfr = *(const bf16x8*)(W2T + (size_t)(n2 + lr) * 512 + ks * 32 + lg * 8);
            #pragma unroll
            for (int mi = 0; mi < 4; ++mi) {
                int row = mi * 16 + lr;
                int off = (row * 1024 + ks * 64 + lg * 16) ^ SWZ(row);
                bf16x8 a2 = *(const bf16x8*)(inA + off);
                acc2[mi] = __builtin_amdgcn_mfma_f32_16x16x32_bf16(a2, bfr, acc2[mi], 0, 0, 0);
            }
        }
        float bb2 = b2[n2 + lr];
        #pragma unroll
        for (int mi = 0; mi < 4; ++mi) {
            #pragma unroll
            for (int rg = 0; rg < 4; ++rg) {
                int row = mi * 16 + lg * 4 + rg;
                int gr = r0 + row;
                if (gr < N_NODES) {
                    size_t idx = (size_t)gr * 128 + n2 + lr;
                    float g = out[idx];
                    g = g > 0.f ? g : expm1f(g);
                    out[idx] = acc2[mi][rg] + bb2 + x[idx] + g;
                }
            }
        }
    }
}

extern "C" void kernel_launch(void* const* d_in, const int* in_sizes, int n_in,
                              void* d_out, int out_size, void* d_ws, size_t ws_size,
                              hipStream_t stream) {
    const float* x     = (const float*)d_in[0];
    const float* Wfc   = (const float*)d_in[1];
    const float* a_l   = (const float*)d_in[2];
    const float* a_r   = (const float*)d_in[3];
    const float* gamma = (const float*)d_in[4];
    const float* beta  = (const float*)d_in[5];
    const float* W1    = (const float*)d_in[6];
    const float* b1    = (const float*)d_in[7];
    const float* W2    = (const float*)d_in[8];
    const float* b2    = (const float*)d_in[9];
    const int*   es    = (const int*)d_in[10];
    const int*   ed    = (const int*)d_in[11];
    float* out = (float*)d_out;

    bf16_t* W1T = (bf16_t*)d_ws;                      // 512*128
    bf16_t* W2T = W1T + 512 * 128;                    // 128*512
    unsigned short* zb = (unsigned short*)(W2T + 128 * 512);  // N*128 bf16
    float* el = (float*)(zb + (size_t)N_NODES * 128); // N*8
    float* er = el + N_NODES * 8;                     // N*8
    int* counts  = (int*)(er + N_NODES * 8);          // N
    int* csr_off = counts + N_NODES;                  // N+1
    int* cursor  = csr_off + N_NODES + 1;             // N+1
    int* csr_src = cursor + N_NODES + 1;              // E
    int* bsum    = csr_src + E_EDGES;                 // SCAN_BLOCKS
    int* boff    = bsum + 128;                        // 128

    k_zero<<<dim3((N_NODES + 255) / 256), dim3(256), 0, stream>>>(counts);
    k_count<<<dim3((E_EDGES + 255) / 256), dim3(256), 0, stream>>>(ed, counts);
    k_scan1<<<dim3(SCAN_BLOCKS), dim3(512), 0, stream>>>(counts, bsum);
    k_scan2<<<dim3(1), dim3(128), 0, stream>>>(bsum, boff);
    k_scan3<<<dim3(SCAN_BLOCKS), dim3(512), 0, stream>>>(counts, boff, csr_off, cursor);
    k_fill<<<dim3((E_EDGES + 255) / 256), dim3(256), 0, stream>>>(es, ed, cursor, csr_src);
    k_prep<<<dim3(256), dim3(256), 0, stream>>>(W1, W2, W1T, W2T);
    k_proj<<<dim3((N_NODES + 63) / 64), dim3(512), 0, stream>>>(x, Wfc, a_l, a_r, zb, el, er);
    k_node<<<dim3((N_NODES + 3) / 4), dim3(256), 0, stream>>>(csr_off, csr_src, el, er, zb, out);
    k_ffn<<<dim3((N_NODES + 63) / 64), dim3(512), 0, stream>>>(x, gamma, beta, W1T, b1, W2T, b2, out);
}